// Round 5
// baseline (667.270 us; speedup 1.0000x reference)
//
#include <hip/hip_runtime.h>

// SiameseGNN round 24: degree-sorted node pairing (perm) for agg kernels.
//
// R23 evidence: doubling edges-in-flight (dwordx2) was NULL (50.6->53.0us)
// -- latency hiding is saturated; residual cost is structural. Padding
// arithmetic: random pairing costs ceil4(max(d0,d1)) ~= 20.1 slots/pair vs
// E[d]=16 useful (~25% sentinel work), and agg1's fused-GEMM2 barrier
// makes block time = max over 4 waves (~44-46 slots vs 35 uniform).
//   fix: process nodes in degree-sorted order. csrb LDS-histograms degrees
//        into 64 global bins; k_dperm (each block re-scans the 64 bins
//        in-wave, then scatters via per-bin atomic cursors) builds perm[].
//        agg1/agg2 take node = perm[pidx]: wave's 4 nodes and block's 16
//        nodes share (near-)equal degree -> max~=d, waste ~5%, uniform
//        barrier. Mean-pool is permutation-invariant; Hs2/As writes were
//        already row-scattered (fused C-write looks up perm[b*16+l], one
//        L1-hot line/block).
// Everything else unchanged from R23 (dwordx2 gathers, scalar guards,
// fused GEMM2, pre-shifted CSR, sentinel row, fp8, wave-scan binA/csrb,
// bucket-major csr, batching, XCD swizzle).

#define TPB    256
#define CHUNK  128
#define SHIFT  7
#define KMAX   1024
#define CAP    2560
#define EPB    8192
#define CPAD   16      // cursorG stride (ints)

typedef __attribute__((ext_vector_type(8))) short short8;
typedef __attribute__((ext_vector_type(4))) float f32x4;
typedef __attribute__((ext_vector_type(2))) float float2v;
typedef __attribute__((ext_vector_type(2))) unsigned int uint2v;

struct Ctx {
    const float* X; const int* esrc; const int* edst;
    unsigned int* temp; unsigned char* Hs2; unsigned char* Hs;
    unsigned int* csr; int* row_ptr; int* degA; float* dinv; int* cursorG;
    int* perm; int* dcnt;   // dcnt[0..63]=bins, dcnt[64..127]=cursors
    float* P; float* P2; float* outp;
};

__device__ __forceinline__ unsigned short f2bf(float x) {
    union { float f; unsigned int i; } c; c.f = x;
    unsigned int r = c.i + 0x7FFFu + ((c.i >> 16) & 1u);   // RNE
    return (unsigned short)(r >> 16);
}
__device__ __forceinline__ unsigned char f2fp8(float x) {
    int p = __builtin_amdgcn_cvt_pk_fp8_f32(x, x, 0, false);
    return (unsigned char)(p & 0xFF);
}
__device__ __forceinline__ float2v up8lo(unsigned int w) {
    return __builtin_amdgcn_cvt_pk_f32_fp8(w, false);
}
__device__ __forceinline__ float2v up8hi(unsigned int w) {
    return __builtin_amdgcn_cvt_pk_f32_fp8(w, true);
}

__global__ void k_prepW2(const float* __restrict__ W1, const float* __restrict__ W2,
                         unsigned short* __restrict__ Wt1, unsigned short* __restrict__ Wt2) {
    const float* W = blockIdx.x ? W2 : W1;
    unsigned short* Wt = blockIdx.x ? Wt2 : Wt1;
    for (int i = threadIdx.x; i < 64 * 64; i += 256) {
        int n = i >> 6, k = i & 63;
        Wt[i] = f2bf(W[k * 64 + n]);
    }
}

// zero cursors + degree bins + the Hs sentinel row (row N)
__global__ void k_zeroCur(Ctx c0, Ctx c1, int nb0, int K, int N) {
    int b = blockIdx.x; Ctx c = c0;
    if (b >= nb0) { c = c1; b -= nb0; }
    int i = b * blockDim.x + threadIdx.x;
    if (i < K) c.cursorG[i * CPAD] = 0;
    if (b == 0 && threadIdx.x < 128) c.dcnt[threadIdx.x] = 0;
    if (b == 0 && threadIdx.x < 64) c.Hs[(size_t)N * 64 + threadIdx.x] = 0;
}

// binA: LDS counting sort per block, burst segment writes. 1024 threads.
__global__ __launch_bounds__(1024) void k_binA(Ctx c0, Ctx c1, int nb0, int E, int K) {
    __shared__ int cnt[KMAX];
    __shared__ int ofs[KMAX];
    __shared__ int segBase[KMAX];
    __shared__ int wsum[16];
    __shared__ unsigned int sorted[EPB];
    __shared__ unsigned short bkt[EPB];
    int b = blockIdx.x; Ctx c = c0;
    if (b >= nb0) { c = c1; b -= nb0; }
    int tid = threadIdx.x;               // 0..1023 == KMAX
    cnt[tid] = 0;
    __syncthreads();
    int base = b * EPB;
    int tot = E - base; if (tot > EPB) tot = EPB;
#pragma unroll
    for (int k = 0; k < EPB / 1024; ++k) {
        int e = base + k * 1024 + tid;
        if (e < E) atomicAdd(&cnt[c.edst[e] >> SHIFT], 1);
    }
    __syncthreads();
    int v = cnt[tid];
    int lane = tid & 63, w = tid >> 6;
    int x = v;                            // wave-inclusive scan
#pragma unroll
    for (int off = 1; off < 64; off <<= 1) {
        int t = __shfl_up(x, off, 64);
        if (lane >= off) x += t;
    }
    if (lane == 63) wsum[w] = x;
    __syncthreads();
    if (tid < 16) {
        int y = wsum[tid];
#pragma unroll
        for (int off = 1; off < 16; off <<= 1) {
            int t = __shfl_up(y, off, 16);
            if ((tid & 15) >= off) y += t;
        }
        wsum[tid] = y;                    // inclusive wave totals
    }
    __syncthreads();
    int pre = w ? wsum[w - 1] : 0;
    ofs[tid] = x + pre - v;               // exclusive scan
    if (tid < K) {
        segBase[tid] = v ? atomicAdd(&c.cursorG[tid * CPAD], v) : 0;
    } else {
        segBase[tid] = 0;
    }
    cnt[tid] = 0;
    __syncthreads();
#pragma unroll
    for (int k = 0; k < EPB / 1024; ++k) {
        int e = base + k * 1024 + tid;
        if (e < E) {
            int d = c.edst[e];
            int bk = d >> SHIFT;
            int r = atomicAdd(&cnt[bk], 1);
            int p = ofs[bk] + r;
            sorted[p] = ((unsigned int)(d & (CHUNK - 1)) << 17) | (unsigned int)c.esrc[e];
            bkt[p] = (unsigned short)bk;
        }
    }
    __syncthreads();
    for (int p = tid; p < tot; p += 1024) {
        unsigned int vv = sorted[p];
        int bk = bkt[p];
        int pos = segBase[bk] + (p - ofs[bk]);
        if (pos < CAP) c.temp[(size_t)bk * CAP + pos] = vv;
    }
}

// Per-bucket LDS counting sort -> bucket-major csr slice (stride CAP) +
// row_ptr (beg) + deg + dinv + degree histogram (64 global bins).
__global__ __launch_bounds__(256) void k_csrb(Ctx c0, Ctx c1, int nb0, int N) {
    __shared__ int deg[CHUNK];
    __shared__ int lofs[CHUNK];
    __shared__ int cur[CHUNK];
    __shared__ int wsum2[2];
    __shared__ int dh[64];
    int b = blockIdx.x; Ctx c = c0;
    if (b >= nb0) { c = c1; b -= nb0; }
    int tid = threadIdx.x;
    if (tid < CHUNK) deg[tid] = 0;
    if (tid >= CHUNK && tid < CHUNK + 64) dh[tid - CHUNK] = 0;
    __syncthreads();
    int cnt = c.cursorG[b * CPAD]; if (cnt > CAP) cnt = CAP;
    const size_t tb = (size_t)b * CAP;
    for (int i = tid; i < cnt; i += 256) atomicAdd(&deg[c.temp[tb + i] >> 17], 1);
    __syncthreads();
    int vdeg = 0, x = 0;
    if (tid < CHUNK) { vdeg = deg[tid]; x = vdeg; }
#pragma unroll
    for (int off = 1; off < 64; off <<= 1) {
        int t = __shfl_up(x, off, 64);
        if ((tid & 63) >= off) x += t;
    }
    if (tid < CHUNK && (tid & 63) == 63) wsum2[tid >> 6] = x;
    __syncthreads();
    int base = b * CAP;                  // bucket-major: no global scan needed
    if (tid < CHUNK) {
        int pre = (tid >> 6) ? wsum2[0] : 0;
        int excl = x + pre - vdeg;
        lofs[tid] = excl;
        cur[tid] = 0;
        int node = b * CHUNK + tid;
        if (node < N) {
            c.row_ptr[node] = base + excl;
            c.degA[node] = vdeg;
            c.dinv[node] = rsqrtf((float)vdeg + 1.0f);
            atomicAdd(&dh[vdeg < 63 ? vdeg : 63], 1);
        }
    }
    __syncthreads();
    if (tid < 64 && dh[tid]) atomicAdd(&c.dcnt[tid], dh[tid]);
    for (int i = tid; i < cnt; i += 256) {
        unsigned int p = c.temp[tb + i];
        int dl = p >> 17;
        int rank = atomicAdd(&cur[dl], 1);
        c.csr[base + lofs[dl] + rank] = (p & 0x1FFFFu) << 6;   // src byte offset
    }
}

// Degree-sorted permutation: each block re-scans the 64 finalized bins
// in-wave (exclusive), then scatters its 256 nodes via per-bin cursors.
__global__ __launch_bounds__(256) void k_dperm(Ctx c0, Ctx c1, int nb0, int N) {
    __shared__ int dbase[64];
    int b = blockIdx.x; Ctx c = c0;
    if (b >= nb0) { c = c1; b -= nb0; }
    if (threadIdx.x < 64) {
        int v = c.dcnt[threadIdx.x];
        int x = v;
#pragma unroll
        for (int off = 1; off < 64; off <<= 1) {
            int t = __shfl_up(x, off, 64);
            if (threadIdx.x >= off) x += t;
        }
        dbase[threadIdx.x] = x - v;       // exclusive scan
    }
    __syncthreads();
    int node = b * 256 + threadIdx.x;
    if (node < N) {
        int dg = c.degA[node];
        int dc = dg < 63 ? dg : 63;
        int pos = dbase[dc] + atomicAdd(&c.dcnt[64 + dc], 1);
        c.perm[pos] = node;
    }
}

// Shared MFMA body: A-fragments provided; B from Wt; store fp8 Hs.
__device__ __forceinline__ void mfma_tail(short8 a0, short8 a1,
                                          const unsigned short* __restrict__ Wt,
                                          unsigned char* __restrict__ Hs,
                                          int row0, int r, int q, int N) {
    short8 bfrag[4][2];
#pragma unroll
    for (int ct = 0; ct < 4; ++ct)
#pragma unroll
        for (int kb = 0; kb < 2; ++kb)
            bfrag[ct][kb] = *(const short8*)(Wt + (ct * 16 + r) * 64 + q * 8 + 32 * kb);
    f32x4 acc[4];
#pragma unroll
    for (int ct = 0; ct < 4; ++ct) {
        acc[ct] = (f32x4){0.0f, 0.0f, 0.0f, 0.0f};
        acc[ct] = __builtin_amdgcn_mfma_f32_16x16x32_bf16(a0, bfrag[ct][0], acc[ct], 0, 0, 0);
        acc[ct] = __builtin_amdgcn_mfma_f32_16x16x32_bf16(a1, bfrag[ct][1], acc[ct], 0, 0, 0);
    }
#pragma unroll
    for (int reg = 0; reg < 4; ++reg) {
        int row = row0 + q * 4 + reg;
        if (row < N) {
            size_t base = (size_t)row * 64 + r;
#pragma unroll
            for (int ct = 0; ct < 4; ++ct)
                Hs[base + ct * 16] = f2fp8(acc[ct][reg]);
        }
    }
}

// GEMM1: fp32 X in, dinv folded into A-fragment conversion.
__global__ __launch_bounds__(256) void k_gemm1(Ctx c0, Ctx c1, int nb0,
                                               const unsigned short* __restrict__ Wt,
                                               int nTiles, int N) {
    int b = blockIdx.x; Ctx c = c0;
    if (b >= nb0) { c = c1; b -= nb0; }
    int wave = threadIdx.x >> 6, lane = threadIdx.x & 63;
    int tile = b * 4 + wave;
    if (tile >= nTiles) return;
    int r = lane & 15, q = lane >> 4;
    int row0 = tile * 16;
    int row = row0 + r;
    int rr = row < N ? row : N - 1;
    float d = c.dinv[rr];
    const float* xrow = c.X + (size_t)rr * 64 + q * 8;
    short8 a0, a1;
#pragma unroll
    for (int j = 0; j < 8; ++j) a0[j] = (short)f2bf(xrow[j] * d);
#pragma unroll
    for (int j = 0; j < 8; ++j) a1[j] = (short)f2bf(xrow[32 + j] * d);
    mfma_tail(a0, a1, Wt, c.Hs, row0, r, q, N);
}

// agg block mapping: XCD-partition swizzle (graph = (blockIdx>>2)&1) when
// swz, else linear split.
__device__ __forceinline__ void agg_map(int bi, int nb0, int swz,
                                        const Ctx& c0, const Ctx& c1,
                                        Ctx& c, int& b) {
    if (swz) {
        int graph = (bi >> 2) & 1;
        b = ((bi >> 3) << 2) | (bi & 3);
        c = graph ? c1 : c0;
    } else {
        b = bi; c = c0;
        if (b >= nb0) { c = c1; b -= nb0; }
    }
}

// 8-deep dwordx2 issue/consume windows; one window = 32 slots (4 edges
// per wave-instruction: 8 subgroups x 8 lanes x 8B). slotbase
// compile-time, lim scalar (SGPR).
__device__ __forceinline__ void agg_issue8w(const unsigned char* __restrict__ Hs,
                                            unsigned int idx, int lim,
                                            int hbase, int j, unsigned int s8,
                                            uint2v* h) {
#pragma unroll
    for (int u = 0; u < 8; ++u) {
        if (4 * u >= lim) break;              // SGPR cmp -> s_cbranch
        unsigned int su = (unsigned int)__shfl((int)idx, hbase + 4 * u + j, 64);
        h[u] = *(const uint2v*)(Hs + (su | s8));
    }
}
__device__ __forceinline__ void agg_cons8w(const uint2v* h, int lim, float2v* acc) {
#pragma unroll
    for (int u = 0; u < 8; ++u) {
        if (4 * u >= lim) break;
        acc[0] += up8lo(h[u][0]); acc[1] += up8hi(h[u][0]);   // sentinel adds 0
        acc[2] += up8lo(h[u][1]); acc[3] += up8hi(h[u][1]);
    }
}

// Two node-pairs per wave, pipelined: both cold idx loads overlap; both
// pairs' first windows are in flight before the first wait. Per half: 4
// subgroups x 8 lanes; lane s covers fp8 channels 8s..8s+7. csr holds
// src<<6; gather offset = su | (s*8). Invalid slots -> sentinel N<<6.
__device__ __forceinline__ void agg_pair2(const unsigned char* __restrict__ Hs,
                                          const unsigned int* __restrict__ csr,
                                          int beg0, int deg0, int maxs0,
                                          int beg1, int deg1, int maxs1,
                                          int lane, unsigned int sent,
                                          float2v* acc0, float2v* acc1) {
    int hbase = lane & 32;
    int hl = lane & 31;
    int j = (hl >> 3) & 3;
    unsigned int s8 = (unsigned int)((lane & 7) * 8);
    unsigned int idx0 = (hl < deg0) ? csr[beg0 + hl] : sent;
    unsigned int idx1 = (hl < deg1) ? csr[beg1 + hl] : sent;
    int lim0 = maxs0 > 32 ? 32 : maxs0;   // scalar
    int lim1 = maxs1 > 32 ? 32 : maxs1;   // scalar
    uint2v h0[8], h1[8];
    agg_issue8w(Hs, idx0, lim0, hbase, j, s8, h0);
    agg_issue8w(Hs, idx1, lim1, hbase, j, s8, h1);
    agg_cons8w(h0, lim0, acc0);
    agg_cons8w(h1, lim1, acc1);
    // rare deep tails (deg > 32)
    for (int base = 32; base < maxs0; base += 32) {
        unsigned int idx = (base + hl < deg0) ? csr[beg0 + base + hl] : sent;
        int lim = maxs0 - base; if (lim > 32) lim = 32;
        uint2v hh[8];
        agg_issue8w(Hs, idx, lim, hbase, j, s8, hh);
        agg_cons8w(hh, lim, acc0);
    }
    for (int base = 32; base < maxs1; base += 32) {
        unsigned int idx = (base + hl < deg1) ? csr[beg1 + base + hl] : sent;
        int lim = maxs1 - base; if (lim > 32) lim = 32;
        uint2v hh[8];
        agg_issue8w(Hs, idx, lim, hbase, j, s8, hh);
        agg_cons8w(hh, lim, acc1);
    }
    // merge the half's 4 subgroups (bits 3,4); does not cross halves
#pragma unroll
    for (int k = 0; k < 4; ++k) {
        float2v o;
        o.x = __shfl_xor(acc0[k].x, 8, 64);  o.y = __shfl_xor(acc0[k].y, 8, 64);
        acc0[k] += o;
        o.x = __shfl_xor(acc0[k].x, 16, 64); o.y = __shfl_xor(acc0[k].y, 16, 64);
        acc0[k] += o;
        o.x = __shfl_xor(acc1[k].x, 8, 64);  o.y = __shfl_xor(acc1[k].y, 8, 64);
        acc1[k] += o;
        o.x = __shfl_xor(acc1[k].x, 16, 64); o.y = __shfl_xor(acc1[k].y, 16, 64);
        acc1[k] += o;
    }
}

// layer-1 + fused GEMM2: block = 16 perm'd nodes (4 waves x 2 pairs).
// v = dinv * relu(b + dinv * agg); rows staged in LDS bf16 (XOR-swizzled
// at 8-element granularity), one barrier, each wave MFMAs one 16-col tile
// of W2, stores fp8 Hs2 at perm'd rows. Hs2 sentinel row zeroed here.
__global__ __launch_bounds__(256, 8) void k_agg1(Ctx c0, Ctx c1, int nb0, int swz,
                                                 const float* __restrict__ bias,
                                                 const unsigned short* __restrict__ Wt2,
                                                 int n) {
    __shared__ unsigned short As[16][64];
    Ctx c; int b;
    agg_map(blockIdx.x, nb0, swz, c0, c1, c, b);
    int wave = threadIdx.x >> 6, lane = threadIdx.x & 63;
    int h = lane >> 5;
    int pbase = b * 16 + wave * 4;
    int pidx0 = pbase + h;
    int pidx1 = pbase + 2 + h;
    int node0 = pidx0 < n ? c.perm[pidx0] : n;
    int node1 = pidx1 < n ? c.perm[pidx1] : n;
    int nd0 = node0 < n ? node0 : 0;
    int nd1 = node1 < n ? node1 : 0;
    int beg0 = c.row_ptr[nd0];
    int beg1 = c.row_ptr[nd1];
    int deg0 = (node0 < n) ? c.degA[nd0] : 0;
    int deg1 = (node1 < n) ? c.degA[nd1] : 0;
    int od0 = __shfl_xor(deg0, 32, 64); int m0 = deg0 > od0 ? deg0 : od0;
    int od1 = __shfl_xor(deg1, 32, 64); int m1 = deg1 > od1 ? deg1 : od1;
    int maxs0 = __builtin_amdgcn_readfirstlane(m0);
    int maxs1 = __builtin_amdgcn_readfirstlane(m1);
    if (b == 0 && threadIdx.x < 64) c.Hs2[(size_t)n * 64 + threadIdx.x] = 0;
    float2v acc0[4] = {{0.f,0.f},{0.f,0.f},{0.f,0.f},{0.f,0.f}};
    float2v acc1[4] = {{0.f,0.f},{0.f,0.f},{0.f,0.f},{0.f,0.f}};
    agg_pair2(c.Hs, c.csr, beg0, deg0, maxs0, beg1, deg1, maxs1,
              lane, (unsigned int)n << 6, acc0, acc1);
    if (((lane >> 3) & 3) == 0) {          // first subgroup of each half
        int s = lane & 7;
#pragma unroll
        for (int pr = 0; pr < 2; ++pr) {
            const float2v* ac = pr ? acc1 : acc0;
            int node = pr ? node1 : node0;
            ushort4 oA = {0, 0, 0, 0}, oB = {0, 0, 0, 0};
            if (node < n) {
                uint2v hv = *(const uint2v*)(c.Hs + (size_t)node * 64 + s * 8);
                float2v h0 = up8lo(hv[0]), h1 = up8hi(hv[0]);
                float2v h2 = up8lo(hv[1]), h3 = up8hi(hv[1]);
                float4 ba = *(const float4*)(bias + s * 8);
                float4 bb = *(const float4*)(bias + s * 8 + 4);
                float d = c.dinv[node];
                oA.x = f2bf(fmaxf(ba.x + d * (ac[0].x + h0.x), 0.0f) * d);
                oA.y = f2bf(fmaxf(ba.y + d * (ac[0].y + h0.y), 0.0f) * d);
                oA.z = f2bf(fmaxf(ba.z + d * (ac[1].x + h1.x), 0.0f) * d);
                oA.w = f2bf(fmaxf(ba.w + d * (ac[1].y + h1.y), 0.0f) * d);
                oB.x = f2bf(fmaxf(bb.x + d * (ac[2].x + h2.x), 0.0f) * d);
                oB.y = f2bf(fmaxf(bb.y + d * (ac[2].y + h2.y), 0.0f) * d);
                oB.z = f2bf(fmaxf(bb.z + d * (ac[3].x + h3.x), 0.0f) * d);
                oB.w = f2bf(fmaxf(bb.w + d * (ac[3].y + h3.y), 0.0f) * d);
            }
            int row = wave * 4 + pr * 2 + h;
            int col = (s * 8) ^ ((row & 7) << 3);
            *(ushort4*)(&As[row][col]) = oA;       // swizzled (8-elem blocks)
            *(ushort4*)(&As[row][col + 4]) = oB;
        }
    }
    __syncthreads();
    // fused GEMM2: wave handles col-tile ct = wave; C rows -> perm'd ids.
    {
        int r = lane & 15, q = lane >> 4;
        int sw = (r & 7) << 3;
        short8 a0 = *(const short8*)(&As[r][(q * 8) ^ sw]);
        short8 a1 = *(const short8*)(&As[r][(q * 8 + 32) ^ sw]);
        const unsigned short* wp = Wt2 + (wave * 16 + r) * 64 + q * 8;
        short8 b0 = *(const short8*)(wp);
        short8 b1 = *(const short8*)(wp + 32);
        f32x4 acc2 = {0.0f, 0.0f, 0.0f, 0.0f};
        acc2 = __builtin_amdgcn_mfma_f32_16x16x32_bf16(a0, b0, acc2, 0, 0, 0);
        acc2 = __builtin_amdgcn_mfma_f32_16x16x32_bf16(a1, b1, acc2, 0, 0, 0);
#pragma unroll
        for (int reg = 0; reg < 4; ++reg) {
            int l = q * 4 + reg;                     // local row 0..15
            int pidx = b * 16 + l;
            if (pidx < n) {
                int row = c.perm[pidx];              // L1-hot line
                c.Hs2[(size_t)row * 64 + wave * 16 + r] = f2fp8(acc2[reg]);
            }
        }
    }
}

// layer-2: block = 16 perm'd nodes; block-reduce 16 relu'd rows ->
// P[block, f] (gathers from Hs2; mean-pool is permutation-invariant)
__global__ __launch_bounds__(256, 8) void k_agg2(Ctx c0, Ctx c1, int nb0, int swz,
                                                 const float* __restrict__ bias, int n) {
    __shared__ float red[16 * 64];
    Ctx c; int b;
    agg_map(blockIdx.x, nb0, swz, c0, c1, c, b);
    int wave = threadIdx.x >> 6, lane = threadIdx.x & 63;
    int h = lane >> 5;
    int pbase = b * 16 + wave * 4;
    int pidx0 = pbase + h;
    int pidx1 = pbase + 2 + h;
    int node0 = pidx0 < n ? c.perm[pidx0] : n;
    int node1 = pidx1 < n ? c.perm[pidx1] : n;
    int nd0 = node0 < n ? node0 : 0;
    int nd1 = node1 < n ? node1 : 0;
    int beg0 = c.row_ptr[nd0];
    int beg1 = c.row_ptr[nd1];
    int deg0 = (node0 < n) ? c.degA[nd0] : 0;
    int deg1 = (node1 < n) ? c.degA[nd1] : 0;
    int od0 = __shfl_xor(deg0, 32, 64); int m0 = deg0 > od0 ? deg0 : od0;
    int od1 = __shfl_xor(deg1, 32, 64); int m1 = deg1 > od1 ? deg1 : od1;
    int maxs0 = __builtin_amdgcn_readfirstlane(m0);
    int maxs1 = __builtin_amdgcn_readfirstlane(m1);
    float2v acc0[4] = {{0.f,0.f},{0.f,0.f},{0.f,0.f},{0.f,0.f}};
    float2v acc1[4] = {{0.f,0.f},{0.f,0.f},{0.f,0.f},{0.f,0.f}};
    agg_pair2(c.Hs2, c.csr, beg0, deg0, maxs0, beg1, deg1, maxs1,
              lane, (unsigned int)n << 6, acc0, acc1);
    if (((lane >> 3) & 3) == 0) {
        int s = lane & 7;
#pragma unroll
        for (int pr = 0; pr < 2; ++pr) {
            const float2v* ac = pr ? acc1 : acc0;
            int node = pr ? node1 : node0;
            float4 vA = {0.f, 0.f, 0.f, 0.f}, vB = {0.f, 0.f, 0.f, 0.f};
            if (node < n) {
                uint2v hv = *(const uint2v*)(c.Hs2 + (size_t)node * 64 + s * 8);
                float2v h0 = up8lo(hv[0]), h1 = up8hi(hv[0]);
                float2v h2 = up8lo(hv[1]), h3 = up8hi(hv[1]);
                float4 ba = *(const float4*)(bias + s * 8);
                float4 bb = *(const float4*)(bias + s * 8 + 4);
                float d = c.dinv[node];
                vA.x = fmaxf(ba.x + d * (ac[0].x + h0.x), 0.0f);
                vA.y = fmaxf(ba.y + d * (ac[0].y + h0.y), 0.0f);
                vA.z = fmaxf(ba.z + d * (ac[1].x + h1.x), 0.0f);
                vA.w = fmaxf(ba.w + d * (ac[1].y + h1.y), 0.0f);
                vB.x = fmaxf(bb.x + d * (ac[2].x + h2.x), 0.0f);
                vB.y = fmaxf(bb.y + d * (ac[2].y + h2.y), 0.0f);
                vB.z = fmaxf(bb.z + d * (ac[3].x + h3.x), 0.0f);
                vB.w = fmaxf(bb.w + d * (ac[3].y + h3.y), 0.0f);
            }
            int row = wave * 4 + pr * 2 + h;
            *(float4*)(&red[row * 64 + s * 8]) = vA;
            *(float4*)(&red[row * 64 + s * 8 + 4]) = vB;
        }
    }
    __syncthreads();
    if (threadIdx.x < 64) {
        float acc16 = 0.0f;
#pragma unroll
        for (int r = 0; r < 16; ++r) acc16 += red[r * 64 + threadIdx.x];
        c.P[(size_t)b * 64 + threadIdx.x] = acc16;
    }
}

// colsum -> per-block partials in P2 (no atomics, no zero pass)
__global__ void k_colsum(Ctx c0, Ctx c1, int nb0, int rows) {
    int b = blockIdx.x; Ctx c = c0;
    if (b >= nb0) { c = c1; b -= nb0; }
    int f = threadIdx.x;  // 64
    float acc = 0.0f;
    for (int r = b; r < rows; r += nb0) acc += c.P[(size_t)r * 64 + f];
    c.P2[b * 64 + f] = acc;
}

// single-wave FC: reduce 256 partial rows, then out = fcb + (S/n) @ fcw^T
__global__ void k_fc(Ctx c0, Ctx c1, const float* __restrict__ fcw,
                     const float* __restrict__ fcb, int n) {
    Ctx c = blockIdx.x ? c1 : c0;
    __shared__ float S[64];
    int j = threadIdx.x;  // 64
    float s = 0.0f;
    for (int r = 0; r < 256; ++r) s += c.P2[r * 64 + j];
    S[j] = s;
    __syncthreads();
    float inv = 1.0f / (float)n;
    float acc = fcb[j];
#pragma unroll
    for (int k = 0; k < 64; ++k) acc += (S[k] * inv) * fcw[j * 64 + k];
    c.outp[j] = acc;
}

extern "C" void kernel_launch(void* const* d_in, const int* in_sizes, int n_in,
                              void* d_out, int out_size, void* d_ws, size_t ws_size,
                              hipStream_t stream) {
    const float* x[2]  = {(const float*)d_in[0], (const float*)d_in[1]};
    const int*   ei[2] = {(const int*)d_in[2], (const int*)d_in[3]};
    const float* W1  = (const float*)d_in[4];
    const float* b1  = (const float*)d_in[5];
    const float* W2  = (const float*)d_in[6];
    const float* b2  = (const float*)d_in[7];
    const float* fcw = (const float*)d_in[8];
    const float* fcb = (const float*)d_in[9];
    float* out = (float*)d_out;

    const int N  = in_sizes[0] / 64;
    const int E  = in_sizes[2] / 2;
    const int NF = N * 64;
    const int K  = (N + CHUNK - 1) / CHUNK;     // 782 buckets
    const int gGm  = (N + 15) / 16;             // aggregate blocks (16 nodes each)
    const int gGmP = (gGm + 3) & ~3;            // padded so swizzle stays legal
    const int nTiles = (N + 15) / 16;
    const int gMf = (nTiles + 3) / 4;
    const int gBin = (E + EPB - 1) / EPB;
    const int gK  = (K + TPB - 1) / TPB;
    const int gPm = (N + 255) / 256;            // dperm blocks

    auto al = [](size_t x) { return (x + 127) & ~(size_t)127; };
    size_t tempB = (size_t)K * CAP * 4;
    size_t hs2B  = (size_t)NF + 64;                    // fp8 + sentinel row N
    size_t szRegion = al(tempB > hs2B ? tempB : hs2B); // Hs2 aliases temp
    size_t szHs  = al((size_t)NF + 64);                // fp8 + sentinel row N
    size_t szCsr = al((size_t)K * CAP * 4);            // bucket-major, stride CAP
    size_t szRp  = al((size_t)N * 4);                  // beg only
    size_t szDeg = al((size_t)N * 4);
    size_t szDi  = al((size_t)N * 4);
    size_t szCu  = al((size_t)K * CPAD * 4);           // padded cursors
    size_t szPerm = al((size_t)N * 4);
    size_t szDc  = al(128 * 4);
    size_t szP   = al((size_t)gGmP * 64 * 4);
    size_t szP2  = al((size_t)256 * 64 * 4);
    size_t setB  = szRegion + szHs + szCsr + szRp + szDeg + szDi + szCu
                 + szPerm + szDc + szP + szP2;
    size_t wtB   = 2 * al(64 * 64 * 2);
    bool batched = ws_size >= wtB + 2 * setB;

    char* base = (char*)d_ws;
    unsigned short* Wt1 = (unsigned short*)base;
    unsigned short* Wt2 = (unsigned short*)(base + al(64 * 64 * 2));

    auto mkctx = [&](int g, char* p) {
        Ctx c;
        c.X = x[g]; c.esrc = ei[g]; c.edst = ei[g] + E;
        c.temp = (unsigned int*)p; c.Hs2 = (unsigned char*)p; p += szRegion;
        c.Hs = (unsigned char*)p; p += szHs;
        c.csr = (unsigned int*)p; p += szCsr;
        c.row_ptr = (int*)p; p += szRp;
        c.degA = (int*)p; p += szDeg;
        c.dinv = (float*)p; p += szDi;
        c.cursorG = (int*)p; p += szCu;
        c.perm = (int*)p; p += szPerm;
        c.dcnt = (int*)p; p += szDc;
        c.P = (float*)p; p += szP;
        c.P2 = (float*)p;
        c.outp = out + g * 64;
        return c;
    };
    char* set0 = base + wtB;
    Ctx c0 = mkctx(0, set0);
    Ctx c1 = mkctx(1, batched ? set0 + setB : set0);   // fallback: shares set0

    k_prepW2<<<2, 256, 0, stream>>>(W1, W2, Wt1, Wt2);

    auto pipe = [&](Ctx A, Ctx B, int mult) {
        int swz = (mult == 2) ? 1 : 0;   // gGmP is always %4 == 0
        k_zeroCur<<<mult * gK, TPB, 0, stream>>>(A, B, gK, K, N);
        k_binA<<<mult * gBin, 1024, 0, stream>>>(A, B, gBin, E, K);
        k_csrb<<<mult * K, 256, 0, stream>>>(A, B, K, N);
        k_dperm<<<mult * gPm, 256, 0, stream>>>(A, B, gPm, N);
        k_gemm1<<<mult * gMf, 256, 0, stream>>>(A, B, gMf, Wt1, nTiles, N);
        k_agg1<<<mult * gGmP, 256, 0, stream>>>(A, B, gGmP, swz, b1, Wt2, N);
        k_agg2<<<mult * gGmP, 256, 0, stream>>>(A, B, gGmP, swz, b2, N);
        k_colsum<<<mult * 256, 64, 0, stream>>>(A, B, 256, gGmP);
        k_fc<<<mult, 64, 0, stream>>>(A, B, fcw, fcb, N);
    };

    if (batched) {
        pipe(c0, c1, 2);
    } else {
        pipe(c0, c0, 1);   // sequential, shared buffer set
        pipe(c1, c1, 1);
    }
}

// Round 6
// 297.726 us; speedup vs baseline: 2.2412x; 2.2412x over previous
//
#include <hip/hip_runtime.h>

// SiameseGNN round 25: perm built locally in csrb (k_dperm deleted).
//
// R24 evidence: k_dperm = ~390us/dispatch (total 281 -> 667us): 100K
// device-scope returning atomicAdds into 64 cursor ints (2 cache lines)
// serialize cross-XCD. The degree-sort idea itself is unmeasured (agg
// deltas hidden under dperm).
//   fix: build perm inside k_csrb with block-local LDS counting sort:
//        64-bin LDS histogram (was already added for R24) + single-wave
//        exclusive scan + LDS-atomic rank scatter ->
//        perm[b*128 + dbase[bin] + rank] = node. No global atomics, +2
//        barriers, k_dperm and dcnt[] deleted. Uniformity is within each
//        128-node chunk; since 16 | 128, every agg block's 16 perm'd
//        nodes fall inside one sorted window (degree spread ~1 for
//        Poisson(16) order stats) -> padding ~ceil4(d)=17.7 slots/pair
//        vs 20.1 random, uniform block barrier.
// Everything else unchanged from R23/R24 (dwordx2 gathers, scalar
// guards, fused GEMM2, pre-shifted CSR, sentinel row, fp8, wave-scan
// binA/csrb, bucket-major csr, batching, XCD swizzle).

#define TPB    256
#define CHUNK  128
#define SHIFT  7
#define KMAX   1024
#define CAP    2560
#define EPB    8192
#define CPAD   16      // cursorG stride (ints)

typedef __attribute__((ext_vector_type(8))) short short8;
typedef __attribute__((ext_vector_type(4))) float f32x4;
typedef __attribute__((ext_vector_type(2))) float float2v;
typedef __attribute__((ext_vector_type(2))) unsigned int uint2v;

struct Ctx {
    const float* X; const int* esrc; const int* edst;
    unsigned int* temp; unsigned char* Hs2; unsigned char* Hs;
    unsigned int* csr; int* row_ptr; int* degA; float* dinv; int* cursorG;
    int* perm;
    float* P; float* P2; float* outp;
};

__device__ __forceinline__ unsigned short f2bf(float x) {
    union { float f; unsigned int i; } c; c.f = x;
    unsigned int r = c.i + 0x7FFFu + ((c.i >> 16) & 1u);   // RNE
    return (unsigned short)(r >> 16);
}
__device__ __forceinline__ unsigned char f2fp8(float x) {
    int p = __builtin_amdgcn_cvt_pk_fp8_f32(x, x, 0, false);
    return (unsigned char)(p & 0xFF);
}
__device__ __forceinline__ float2v up8lo(unsigned int w) {
    return __builtin_amdgcn_cvt_pk_f32_fp8(w, false);
}
__device__ __forceinline__ float2v up8hi(unsigned int w) {
    return __builtin_amdgcn_cvt_pk_f32_fp8(w, true);
}

__global__ void k_prepW2(const float* __restrict__ W1, const float* __restrict__ W2,
                         unsigned short* __restrict__ Wt1, unsigned short* __restrict__ Wt2) {
    const float* W = blockIdx.x ? W2 : W1;
    unsigned short* Wt = blockIdx.x ? Wt2 : Wt1;
    for (int i = threadIdx.x; i < 64 * 64; i += 256) {
        int n = i >> 6, k = i & 63;
        Wt[i] = f2bf(W[k * 64 + n]);
    }
}

// zero cursors + the Hs sentinel row (row N; ws re-poisoned per call)
__global__ void k_zeroCur(Ctx c0, Ctx c1, int nb0, int K, int N) {
    int b = blockIdx.x; Ctx c = c0;
    if (b >= nb0) { c = c1; b -= nb0; }
    int i = b * blockDim.x + threadIdx.x;
    if (i < K) c.cursorG[i * CPAD] = 0;
    if (b == 0 && threadIdx.x < 64) c.Hs[(size_t)N * 64 + threadIdx.x] = 0;
}

// binA: LDS counting sort per block, burst segment writes. 1024 threads.
__global__ __launch_bounds__(1024) void k_binA(Ctx c0, Ctx c1, int nb0, int E, int K) {
    __shared__ int cnt[KMAX];
    __shared__ int ofs[KMAX];
    __shared__ int segBase[KMAX];
    __shared__ int wsum[16];
    __shared__ unsigned int sorted[EPB];
    __shared__ unsigned short bkt[EPB];
    int b = blockIdx.x; Ctx c = c0;
    if (b >= nb0) { c = c1; b -= nb0; }
    int tid = threadIdx.x;               // 0..1023 == KMAX
    cnt[tid] = 0;
    __syncthreads();
    int base = b * EPB;
    int tot = E - base; if (tot > EPB) tot = EPB;
#pragma unroll
    for (int k = 0; k < EPB / 1024; ++k) {
        int e = base + k * 1024 + tid;
        if (e < E) atomicAdd(&cnt[c.edst[e] >> SHIFT], 1);
    }
    __syncthreads();
    int v = cnt[tid];
    int lane = tid & 63, w = tid >> 6;
    int x = v;                            // wave-inclusive scan
#pragma unroll
    for (int off = 1; off < 64; off <<= 1) {
        int t = __shfl_up(x, off, 64);
        if (lane >= off) x += t;
    }
    if (lane == 63) wsum[w] = x;
    __syncthreads();
    if (tid < 16) {
        int y = wsum[tid];
#pragma unroll
        for (int off = 1; off < 16; off <<= 1) {
            int t = __shfl_up(y, off, 16);
            if ((tid & 15) >= off) y += t;
        }
        wsum[tid] = y;                    // inclusive wave totals
    }
    __syncthreads();
    int pre = w ? wsum[w - 1] : 0;
    ofs[tid] = x + pre - v;               // exclusive scan
    if (tid < K) {
        segBase[tid] = v ? atomicAdd(&c.cursorG[tid * CPAD], v) : 0;
    } else {
        segBase[tid] = 0;
    }
    cnt[tid] = 0;
    __syncthreads();
#pragma unroll
    for (int k = 0; k < EPB / 1024; ++k) {
        int e = base + k * 1024 + tid;
        if (e < E) {
            int d = c.edst[e];
            int bk = d >> SHIFT;
            int r = atomicAdd(&cnt[bk], 1);
            int p = ofs[bk] + r;
            sorted[p] = ((unsigned int)(d & (CHUNK - 1)) << 17) | (unsigned int)c.esrc[e];
            bkt[p] = (unsigned short)bk;
        }
    }
    __syncthreads();
    for (int p = tid; p < tot; p += 1024) {
        unsigned int vv = sorted[p];
        int bk = bkt[p];
        int pos = segBase[bk] + (p - ofs[bk]);
        if (pos < CAP) c.temp[(size_t)bk * CAP + pos] = vv;
    }
}

// Per-bucket LDS counting sort -> bucket-major csr slice (stride CAP) +
// row_ptr (beg) + deg + dinv + block-local degree-sorted perm slice.
__global__ __launch_bounds__(256) void k_csrb(Ctx c0, Ctx c1, int nb0, int N) {
    __shared__ int deg[CHUNK];
    __shared__ int lofs[CHUNK];
    __shared__ int cur[CHUNK];
    __shared__ int wsum2[2];
    __shared__ int dh[64];
    __shared__ int pcur[64];
    int b = blockIdx.x; Ctx c = c0;
    if (b >= nb0) { c = c1; b -= nb0; }
    int tid = threadIdx.x;
    if (tid < CHUNK) deg[tid] = 0;
    if (tid >= CHUNK && tid < CHUNK + 64) dh[tid - CHUNK] = 0;
    if (tid >= CHUNK + 64 && tid < CHUNK + 128) pcur[tid - CHUNK - 64] = 0;
    __syncthreads();
    int cnt = c.cursorG[b * CPAD]; if (cnt > CAP) cnt = CAP;
    const size_t tb = (size_t)b * CAP;
    for (int i = tid; i < cnt; i += 256) atomicAdd(&deg[c.temp[tb + i] >> 17], 1);
    __syncthreads();
    int vdeg = 0, x = 0;
    if (tid < CHUNK) { vdeg = deg[tid]; x = vdeg; }
#pragma unroll
    for (int off = 1; off < 64; off <<= 1) {
        int t = __shfl_up(x, off, 64);
        if ((tid & 63) >= off) x += t;
    }
    if (tid < CHUNK && (tid & 63) == 63) wsum2[tid >> 6] = x;
    __syncthreads();
    int base = b * CAP;                  // bucket-major: no global scan needed
    int dc = vdeg < 63 ? vdeg : 63;
    if (tid < CHUNK) {
        int pre = (tid >> 6) ? wsum2[0] : 0;
        int excl = x + pre - vdeg;
        lofs[tid] = excl;
        cur[tid] = 0;
        int node = b * CHUNK + tid;
        if (node < N) {
            c.row_ptr[node] = base + excl;
            c.degA[node] = vdeg;
            c.dinv[node] = rsqrtf((float)vdeg + 1.0f);
            atomicAdd(&dh[dc], 1);
        }
    }
    __syncthreads();
    if (tid < 64) {                      // exclusive scan of 64 bins (1 wave)
        int v = dh[tid];
        int y = v;
#pragma unroll
        for (int off = 1; off < 64; off <<= 1) {
            int t = __shfl_up(y, off, 64);
            if (tid >= off) y += t;
        }
        dh[tid] = y - v;                 // exclusive base
    }
    __syncthreads();
    if (tid < CHUNK) {
        int node = b * CHUNK + tid;
        if (node < N) {
            int rank = atomicAdd(&pcur[dc], 1);
            c.perm[b * CHUNK + dh[dc] + rank] = node;
        }
    }
    for (int i = tid; i < cnt; i += 256) {
        unsigned int p = c.temp[tb + i];
        int dl = p >> 17;
        int rank = atomicAdd(&cur[dl], 1);
        c.csr[base + lofs[dl] + rank] = (p & 0x1FFFFu) << 6;   // src byte offset
    }
}

// Shared MFMA body: A-fragments provided; B from Wt; store fp8 Hs.
__device__ __forceinline__ void mfma_tail(short8 a0, short8 a1,
                                          const unsigned short* __restrict__ Wt,
                                          unsigned char* __restrict__ Hs,
                                          int row0, int r, int q, int N) {
    short8 bfrag[4][2];
#pragma unroll
    for (int ct = 0; ct < 4; ++ct)
#pragma unroll
        for (int kb = 0; kb < 2; ++kb)
            bfrag[ct][kb] = *(const short8*)(Wt + (ct * 16 + r) * 64 + q * 8 + 32 * kb);
    f32x4 acc[4];
#pragma unroll
    for (int ct = 0; ct < 4; ++ct) {
        acc[ct] = (f32x4){0.0f, 0.0f, 0.0f, 0.0f};
        acc[ct] = __builtin_amdgcn_mfma_f32_16x16x32_bf16(a0, bfrag[ct][0], acc[ct], 0, 0, 0);
        acc[ct] = __builtin_amdgcn_mfma_f32_16x16x32_bf16(a1, bfrag[ct][1], acc[ct], 0, 0, 0);
    }
#pragma unroll
    for (int reg = 0; reg < 4; ++reg) {
        int row = row0 + q * 4 + reg;
        if (row < N) {
            size_t base = (size_t)row * 64 + r;
#pragma unroll
            for (int ct = 0; ct < 4; ++ct)
                Hs[base + ct * 16] = f2fp8(acc[ct][reg]);
        }
    }
}

// GEMM1: fp32 X in, dinv folded into A-fragment conversion.
__global__ __launch_bounds__(256) void k_gemm1(Ctx c0, Ctx c1, int nb0,
                                               const unsigned short* __restrict__ Wt,
                                               int nTiles, int N) {
    int b = blockIdx.x; Ctx c = c0;
    if (b >= nb0) { c = c1; b -= nb0; }
    int wave = threadIdx.x >> 6, lane = threadIdx.x & 63;
    int tile = b * 4 + wave;
    if (tile >= nTiles) return;
    int r = lane & 15, q = lane >> 4;
    int row0 = tile * 16;
    int row = row0 + r;
    int rr = row < N ? row : N - 1;
    float d = c.dinv[rr];
    const float* xrow = c.X + (size_t)rr * 64 + q * 8;
    short8 a0, a1;
#pragma unroll
    for (int j = 0; j < 8; ++j) a0[j] = (short)f2bf(xrow[j] * d);
#pragma unroll
    for (int j = 0; j < 8; ++j) a1[j] = (short)f2bf(xrow[32 + j] * d);
    mfma_tail(a0, a1, Wt, c.Hs, row0, r, q, N);
}

// agg block mapping: XCD-partition swizzle (graph = (blockIdx>>2)&1) when
// swz, else linear split.
__device__ __forceinline__ void agg_map(int bi, int nb0, int swz,
                                        const Ctx& c0, const Ctx& c1,
                                        Ctx& c, int& b) {
    if (swz) {
        int graph = (bi >> 2) & 1;
        b = ((bi >> 3) << 2) | (bi & 3);
        c = graph ? c1 : c0;
    } else {
        b = bi; c = c0;
        if (b >= nb0) { c = c1; b -= nb0; }
    }
}

// 8-deep dwordx2 issue/consume windows; one window = 32 slots (4 edges
// per wave-instruction: 8 subgroups x 8 lanes x 8B). slotbase
// compile-time, lim scalar (SGPR).
__device__ __forceinline__ void agg_issue8w(const unsigned char* __restrict__ Hs,
                                            unsigned int idx, int lim,
                                            int hbase, int j, unsigned int s8,
                                            uint2v* h) {
#pragma unroll
    for (int u = 0; u < 8; ++u) {
        if (4 * u >= lim) break;              // SGPR cmp -> s_cbranch
        unsigned int su = (unsigned int)__shfl((int)idx, hbase + 4 * u + j, 64);
        h[u] = *(const uint2v*)(Hs + (su | s8));
    }
}
__device__ __forceinline__ void agg_cons8w(const uint2v* h, int lim, float2v* acc) {
#pragma unroll
    for (int u = 0; u < 8; ++u) {
        if (4 * u >= lim) break;
        acc[0] += up8lo(h[u][0]); acc[1] += up8hi(h[u][0]);   // sentinel adds 0
        acc[2] += up8lo(h[u][1]); acc[3] += up8hi(h[u][1]);
    }
}

// Two node-pairs per wave, pipelined: both cold idx loads overlap; both
// pairs' first windows are in flight before the first wait. Per half: 4
// subgroups x 8 lanes; lane s covers fp8 channels 8s..8s+7. csr holds
// src<<6; gather offset = su | (s*8). Invalid slots -> sentinel N<<6.
__device__ __forceinline__ void agg_pair2(const unsigned char* __restrict__ Hs,
                                          const unsigned int* __restrict__ csr,
                                          int beg0, int deg0, int maxs0,
                                          int beg1, int deg1, int maxs1,
                                          int lane, unsigned int sent,
                                          float2v* acc0, float2v* acc1) {
    int hbase = lane & 32;
    int hl = lane & 31;
    int j = (hl >> 3) & 3;
    unsigned int s8 = (unsigned int)((lane & 7) * 8);
    unsigned int idx0 = (hl < deg0) ? csr[beg0 + hl] : sent;
    unsigned int idx1 = (hl < deg1) ? csr[beg1 + hl] : sent;
    int lim0 = maxs0 > 32 ? 32 : maxs0;   // scalar
    int lim1 = maxs1 > 32 ? 32 : maxs1;   // scalar
    uint2v h0[8], h1[8];
    agg_issue8w(Hs, idx0, lim0, hbase, j, s8, h0);
    agg_issue8w(Hs, idx1, lim1, hbase, j, s8, h1);
    agg_cons8w(h0, lim0, acc0);
    agg_cons8w(h1, lim1, acc1);
    // rare deep tails (deg > 32)
    for (int base = 32; base < maxs0; base += 32) {
        unsigned int idx = (base + hl < deg0) ? csr[beg0 + base + hl] : sent;
        int lim = maxs0 - base; if (lim > 32) lim = 32;
        uint2v hh[8];
        agg_issue8w(Hs, idx, lim, hbase, j, s8, hh);
        agg_cons8w(hh, lim, acc0);
    }
    for (int base = 32; base < maxs1; base += 32) {
        unsigned int idx = (base + hl < deg1) ? csr[beg1 + base + hl] : sent;
        int lim = maxs1 - base; if (lim > 32) lim = 32;
        uint2v hh[8];
        agg_issue8w(Hs, idx, lim, hbase, j, s8, hh);
        agg_cons8w(hh, lim, acc1);
    }
    // merge the half's 4 subgroups (bits 3,4); does not cross halves
#pragma unroll
    for (int k = 0; k < 4; ++k) {
        float2v o;
        o.x = __shfl_xor(acc0[k].x, 8, 64);  o.y = __shfl_xor(acc0[k].y, 8, 64);
        acc0[k] += o;
        o.x = __shfl_xor(acc0[k].x, 16, 64); o.y = __shfl_xor(acc0[k].y, 16, 64);
        acc0[k] += o;
        o.x = __shfl_xor(acc1[k].x, 8, 64);  o.y = __shfl_xor(acc1[k].y, 8, 64);
        acc1[k] += o;
        o.x = __shfl_xor(acc1[k].x, 16, 64); o.y = __shfl_xor(acc1[k].y, 16, 64);
        acc1[k] += o;
    }
}

// layer-1 + fused GEMM2: block = 16 perm'd nodes (4 waves x 2 pairs).
// v = dinv * relu(b + dinv * agg); rows staged in LDS bf16 (XOR-swizzled
// at 8-element granularity), one barrier, each wave MFMAs one 16-col tile
// of W2, stores fp8 Hs2 at perm'd rows. Hs2 sentinel row zeroed here.
__global__ __launch_bounds__(256, 8) void k_agg1(Ctx c0, Ctx c1, int nb0, int swz,
                                                 const float* __restrict__ bias,
                                                 const unsigned short* __restrict__ Wt2,
                                                 int n) {
    __shared__ unsigned short As[16][64];
    Ctx c; int b;
    agg_map(blockIdx.x, nb0, swz, c0, c1, c, b);
    int wave = threadIdx.x >> 6, lane = threadIdx.x & 63;
    int h = lane >> 5;
    int pbase = b * 16 + wave * 4;
    int pidx0 = pbase + h;
    int pidx1 = pbase + 2 + h;
    int node0 = pidx0 < n ? c.perm[pidx0] : n;
    int node1 = pidx1 < n ? c.perm[pidx1] : n;
    int nd0 = node0 < n ? node0 : 0;
    int nd1 = node1 < n ? node1 : 0;
    int beg0 = c.row_ptr[nd0];
    int beg1 = c.row_ptr[nd1];
    int deg0 = (node0 < n) ? c.degA[nd0] : 0;
    int deg1 = (node1 < n) ? c.degA[nd1] : 0;
    int od0 = __shfl_xor(deg0, 32, 64); int m0 = deg0 > od0 ? deg0 : od0;
    int od1 = __shfl_xor(deg1, 32, 64); int m1 = deg1 > od1 ? deg1 : od1;
    int maxs0 = __builtin_amdgcn_readfirstlane(m0);
    int maxs1 = __builtin_amdgcn_readfirstlane(m1);
    if (b == 0 && threadIdx.x < 64) c.Hs2[(size_t)n * 64 + threadIdx.x] = 0;
    float2v acc0[4] = {{0.f,0.f},{0.f,0.f},{0.f,0.f},{0.f,0.f}};
    float2v acc1[4] = {{0.f,0.f},{0.f,0.f},{0.f,0.f},{0.f,0.f}};
    agg_pair2(c.Hs, c.csr, beg0, deg0, maxs0, beg1, deg1, maxs1,
              lane, (unsigned int)n << 6, acc0, acc1);
    if (((lane >> 3) & 3) == 0) {          // first subgroup of each half
        int s = lane & 7;
#pragma unroll
        for (int pr = 0; pr < 2; ++pr) {
            const float2v* ac = pr ? acc1 : acc0;
            int node = pr ? node1 : node0;
            ushort4 oA = {0, 0, 0, 0}, oB = {0, 0, 0, 0};
            if (node < n) {
                uint2v hv = *(const uint2v*)(c.Hs + (size_t)node * 64 + s * 8);
                float2v h0 = up8lo(hv[0]), h1 = up8hi(hv[0]);
                float2v h2 = up8lo(hv[1]), h3 = up8hi(hv[1]);
                float4 ba = *(const float4*)(bias + s * 8);
                float4 bb = *(const float4*)(bias + s * 8 + 4);
                float d = c.dinv[node];
                oA.x = f2bf(fmaxf(ba.x + d * (ac[0].x + h0.x), 0.0f) * d);
                oA.y = f2bf(fmaxf(ba.y + d * (ac[0].y + h0.y), 0.0f) * d);
                oA.z = f2bf(fmaxf(ba.z + d * (ac[1].x + h1.x), 0.0f) * d);
                oA.w = f2bf(fmaxf(ba.w + d * (ac[1].y + h1.y), 0.0f) * d);
                oB.x = f2bf(fmaxf(bb.x + d * (ac[2].x + h2.x), 0.0f) * d);
                oB.y = f2bf(fmaxf(bb.y + d * (ac[2].y + h2.y), 0.0f) * d);
                oB.z = f2bf(fmaxf(bb.z + d * (ac[3].x + h3.x), 0.0f) * d);
                oB.w = f2bf(fmaxf(bb.w + d * (ac[3].y + h3.y), 0.0f) * d);
            }
            int row = wave * 4 + pr * 2 + h;
            int col = (s * 8) ^ ((row & 7) << 3);
            *(ushort4*)(&As[row][col]) = oA;       // swizzled (8-elem blocks)
            *(ushort4*)(&As[row][col + 4]) = oB;
        }
    }
    __syncthreads();
    // fused GEMM2: wave handles col-tile ct = wave; C rows -> perm'd ids.
    {
        int r = lane & 15, q = lane >> 4;
        int sw = (r & 7) << 3;
        short8 a0 = *(const short8*)(&As[r][(q * 8) ^ sw]);
        short8 a1 = *(const short8*)(&As[r][(q * 8 + 32) ^ sw]);
        const unsigned short* wp = Wt2 + (wave * 16 + r) * 64 + q * 8;
        short8 b0 = *(const short8*)(wp);
        short8 b1 = *(const short8*)(wp + 32);
        f32x4 acc2 = {0.0f, 0.0f, 0.0f, 0.0f};
        acc2 = __builtin_amdgcn_mfma_f32_16x16x32_bf16(a0, b0, acc2, 0, 0, 0);
        acc2 = __builtin_amdgcn_mfma_f32_16x16x32_bf16(a1, b1, acc2, 0, 0, 0);
#pragma unroll
        for (int reg = 0; reg < 4; ++reg) {
            int l = q * 4 + reg;                     // local row 0..15
            int pidx = b * 16 + l;
            if (pidx < n) {
                int row = c.perm[pidx];              // L1-hot line
                c.Hs2[(size_t)row * 64 + wave * 16 + r] = f2fp8(acc2[reg]);
            }
        }
    }
}

// layer-2: block = 16 perm'd nodes; block-reduce 16 relu'd rows ->
// P[block, f] (gathers from Hs2; mean-pool is permutation-invariant)
__global__ __launch_bounds__(256, 8) void k_agg2(Ctx c0, Ctx c1, int nb0, int swz,
                                                 const float* __restrict__ bias, int n) {
    __shared__ float red[16 * 64];
    Ctx c; int b;
    agg_map(blockIdx.x, nb0, swz, c0, c1, c, b);
    int wave = threadIdx.x >> 6, lane = threadIdx.x & 63;
    int h = lane >> 5;
    int pbase = b * 16 + wave * 4;
    int pidx0 = pbase + h;
    int pidx1 = pbase + 2 + h;
    int node0 = pidx0 < n ? c.perm[pidx0] : n;
    int node1 = pidx1 < n ? c.perm[pidx1] : n;
    int nd0 = node0 < n ? node0 : 0;
    int nd1 = node1 < n ? node1 : 0;
    int beg0 = c.row_ptr[nd0];
    int beg1 = c.row_ptr[nd1];
    int deg0 = (node0 < n) ? c.degA[nd0] : 0;
    int deg1 = (node1 < n) ? c.degA[nd1] : 0;
    int od0 = __shfl_xor(deg0, 32, 64); int m0 = deg0 > od0 ? deg0 : od0;
    int od1 = __shfl_xor(deg1, 32, 64); int m1 = deg1 > od1 ? deg1 : od1;
    int maxs0 = __builtin_amdgcn_readfirstlane(m0);
    int maxs1 = __builtin_amdgcn_readfirstlane(m1);
    float2v acc0[4] = {{0.f,0.f},{0.f,0.f},{0.f,0.f},{0.f,0.f}};
    float2v acc1[4] = {{0.f,0.f},{0.f,0.f},{0.f,0.f},{0.f,0.f}};
    agg_pair2(c.Hs2, c.csr, beg0, deg0, maxs0, beg1, deg1, maxs1,
              lane, (unsigned int)n << 6, acc0, acc1);
    if (((lane >> 3) & 3) == 0) {
        int s = lane & 7;
#pragma unroll
        for (int pr = 0; pr < 2; ++pr) {
            const float2v* ac = pr ? acc1 : acc0;
            int node = pr ? node1 : node0;
            float4 vA = {0.f, 0.f, 0.f, 0.f}, vB = {0.f, 0.f, 0.f, 0.f};
            if (node < n) {
                uint2v hv = *(const uint2v*)(c.Hs2 + (size_t)node * 64 + s * 8);
                float2v h0 = up8lo(hv[0]), h1 = up8hi(hv[0]);
                float2v h2 = up8lo(hv[1]), h3 = up8hi(hv[1]);
                float4 ba = *(const float4*)(bias + s * 8);
                float4 bb = *(const float4*)(bias + s * 8 + 4);
                float d = c.dinv[node];
                vA.x = fmaxf(ba.x + d * (ac[0].x + h0.x), 0.0f);
                vA.y = fmaxf(ba.y + d * (ac[0].y + h0.y), 0.0f);
                vA.z = fmaxf(ba.z + d * (ac[1].x + h1.x), 0.0f);
                vA.w = fmaxf(ba.w + d * (ac[1].y + h1.y), 0.0f);
                vB.x = fmaxf(bb.x + d * (ac[2].x + h2.x), 0.0f);
                vB.y = fmaxf(bb.y + d * (ac[2].y + h2.y), 0.0f);
                vB.z = fmaxf(bb.z + d * (ac[3].x + h3.x), 0.0f);
                vB.w = fmaxf(bb.w + d * (ac[3].y + h3.y), 0.0f);
            }
            int row = wave * 4 + pr * 2 + h;
            *(float4*)(&red[row * 64 + s * 8]) = vA;
            *(float4*)(&red[row * 64 + s * 8 + 4]) = vB;
        }
    }
    __syncthreads();
    if (threadIdx.x < 64) {
        float acc16 = 0.0f;
#pragma unroll
        for (int r = 0; r < 16; ++r) acc16 += red[r * 64 + threadIdx.x];
        c.P[(size_t)b * 64 + threadIdx.x] = acc16;
    }
}

// colsum -> per-block partials in P2 (no atomics, no zero pass)
__global__ void k_colsum(Ctx c0, Ctx c1, int nb0, int rows) {
    int b = blockIdx.x; Ctx c = c0;
    if (b >= nb0) { c = c1; b -= nb0; }
    int f = threadIdx.x;  // 64
    float acc = 0.0f;
    for (int r = b; r < rows; r += nb0) acc += c.P[(size_t)r * 64 + f];
    c.P2[b * 64 + f] = acc;
}

// single-wave FC: reduce 256 partial rows, then out = fcb + (S/n) @ fcw^T
__global__ void k_fc(Ctx c0, Ctx c1, const float* __restrict__ fcw,
                     const float* __restrict__ fcb, int n) {
    Ctx c = blockIdx.x ? c1 : c0;
    __shared__ float S[64];
    int j = threadIdx.x;  // 64
    float s = 0.0f;
    for (int r = 0; r < 256; ++r) s += c.P2[r * 64 + j];
    S[j] = s;
    __syncthreads();
    float inv = 1.0f / (float)n;
    float acc = fcb[j];
#pragma unroll
    for (int k = 0; k < 64; ++k) acc += (S[k] * inv) * fcw[j * 64 + k];
    c.outp[j] = acc;
}

extern "C" void kernel_launch(void* const* d_in, const int* in_sizes, int n_in,
                              void* d_out, int out_size, void* d_ws, size_t ws_size,
                              hipStream_t stream) {
    const float* x[2]  = {(const float*)d_in[0], (const float*)d_in[1]};
    const int*   ei[2] = {(const int*)d_in[2], (const int*)d_in[3]};
    const float* W1  = (const float*)d_in[4];
    const float* b1  = (const float*)d_in[5];
    const float* W2  = (const float*)d_in[6];
    const float* b2  = (const float*)d_in[7];
    const float* fcw = (const float*)d_in[8];
    const float* fcb = (const float*)d_in[9];
    float* out = (float*)d_out;

    const int N  = in_sizes[0] / 64;
    const int E  = in_sizes[2] / 2;
    const int NF = N * 64;
    const int K  = (N + CHUNK - 1) / CHUNK;     // 782 buckets
    const int gGm  = (N + 15) / 16;             // aggregate blocks (16 nodes each)
    const int gGmP = (gGm + 3) & ~3;            // padded so swizzle stays legal
    const int nTiles = (N + 15) / 16;
    const int gMf = (nTiles + 3) / 4;
    const int gBin = (E + EPB - 1) / EPB;
    const int gK  = (K + TPB - 1) / TPB;

    auto al = [](size_t x) { return (x + 127) & ~(size_t)127; };
    size_t tempB = (size_t)K * CAP * 4;
    size_t hs2B  = (size_t)NF + 64;                    // fp8 + sentinel row N
    size_t szRegion = al(tempB > hs2B ? tempB : hs2B); // Hs2 aliases temp
    size_t szHs  = al((size_t)NF + 64);                // fp8 + sentinel row N
    size_t szCsr = al((size_t)K * CAP * 4);            // bucket-major, stride CAP
    size_t szRp  = al((size_t)N * 4);                  // beg only
    size_t szDeg = al((size_t)N * 4);
    size_t szDi  = al((size_t)N * 4);
    size_t szCu  = al((size_t)K * CPAD * 4);           // padded cursors
    size_t szPerm = al((size_t)K * CHUNK * 4);         // chunk-padded perm
    size_t szP   = al((size_t)gGmP * 64 * 4);
    size_t szP2  = al((size_t)256 * 64 * 4);
    size_t setB  = szRegion + szHs + szCsr + szRp + szDeg + szDi + szCu
                 + szPerm + szP + szP2;
    size_t wtB   = 2 * al(64 * 64 * 2);
    bool batched = ws_size >= wtB + 2 * setB;

    char* base = (char*)d_ws;
    unsigned short* Wt1 = (unsigned short*)base;
    unsigned short* Wt2 = (unsigned short*)(base + al(64 * 64 * 2));

    auto mkctx = [&](int g, char* p) {
        Ctx c;
        c.X = x[g]; c.esrc = ei[g]; c.edst = ei[g] + E;
        c.temp = (unsigned int*)p; c.Hs2 = (unsigned char*)p; p += szRegion;
        c.Hs = (unsigned char*)p; p += szHs;
        c.csr = (unsigned int*)p; p += szCsr;
        c.row_ptr = (int*)p; p += szRp;
        c.degA = (int*)p; p += szDeg;
        c.dinv = (float*)p; p += szDi;
        c.cursorG = (int*)p; p += szCu;
        c.perm = (int*)p; p += szPerm;
        c.P = (float*)p; p += szP;
        c.P2 = (float*)p;
        c.outp = out + g * 64;
        return c;
    };
    char* set0 = base + wtB;
    Ctx c0 = mkctx(0, set0);
    Ctx c1 = mkctx(1, batched ? set0 + setB : set0);   // fallback: shares set0

    k_prepW2<<<2, 256, 0, stream>>>(W1, W2, Wt1, Wt2);

    auto pipe = [&](Ctx A, Ctx B, int mult) {
        int swz = (mult == 2) ? 1 : 0;   // gGmP is always %4 == 0
        k_zeroCur<<<mult * gK, TPB, 0, stream>>>(A, B, gK, K, N);
        k_binA<<<mult * gBin, 1024, 0, stream>>>(A, B, gBin, E, K);
        k_csrb<<<mult * K, 256, 0, stream>>>(A, B, K, N);
        k_gemm1<<<mult * gMf, 256, 0, stream>>>(A, B, gMf, Wt1, nTiles, N);
        k_agg1<<<mult * gGmP, 256, 0, stream>>>(A, B, gGmP, swz, b1, Wt2, N);
        k_agg2<<<mult * gGmP, 256, 0, stream>>>(A, B, gGmP, swz, b2, N);
        k_colsum<<<mult * 256, 64, 0, stream>>>(A, B, 256, gGmP);
        k_fc<<<mult, 64, 0, stream>>>(A, B, fcw, fcb, N);
    };

    if (batched) {
        pipe(c0, c1, 2);
    } else {
        pipe(c0, c0, 1);   // sequential, shared buffer set
        pipe(c1, c1, 1);
    }
}

// Round 7
// 287.895 us; speedup vs baseline: 2.3178x; 1.0341x over previous
//
#include <hip/hip_runtime.h>

// SiameseGNN round 26: revert perm; block-LOCAL degree-balanced wave
// assignment (locality-preserving load balance).
//
// R25 evidence: global/chunk perm HURT (agg1 53->64us, FETCH 100->122MB):
// scattered csr rows (partial-line waste) + scattered Hs2 row writes
// (write-allocate RMW fetches) outweighed the padding win.
//   fix: keep each agg block's 16 CONTIGUOUS nodes (exact R23 locality);
//        rebalance only the intra-block wave assignment in LDS:
//        - read 16 degs (1 coalesced line) -> sdeg[]
//        - rank by 16x16 comparison count (16 threads, trivial)
//        - pair rank-adjacent nodes (2q,2q+1): pair-max ~= pair-min
//        - snake pairs onto waves (wave w: pairs q=w and q=7-w):
//          per-wave slot totals uniform -> block completion ~47 -> ~39
//          slots (-15-18%) with unchanged memory behavior.
//        agg1 fused-GEMM2 C-write maps slot->node via snode[] (LDS).
// Everything else = R23 (dwordx2 gathers, scalar guards, fused GEMM2,
// pre-shifted CSR, sentinel row, fp8, wave-scan binA/csrb, bucket-major
// csr, batching, XCD swizzle).

#define TPB    256
#define CHUNK  128
#define SHIFT  7
#define KMAX   1024
#define CAP    2560
#define EPB    8192
#define CPAD   16      // cursorG stride (ints)

typedef __attribute__((ext_vector_type(8))) short short8;
typedef __attribute__((ext_vector_type(4))) float f32x4;
typedef __attribute__((ext_vector_type(2))) float float2v;
typedef __attribute__((ext_vector_type(2))) unsigned int uint2v;

struct Ctx {
    const float* X; const int* esrc; const int* edst;
    unsigned int* temp; unsigned char* Hs2; unsigned char* Hs;
    unsigned int* csr; int* row_ptr; int* degA; float* dinv; int* cursorG;
    float* P; float* P2; float* outp;
};

__device__ __forceinline__ unsigned short f2bf(float x) {
    union { float f; unsigned int i; } c; c.f = x;
    unsigned int r = c.i + 0x7FFFu + ((c.i >> 16) & 1u);   // RNE
    return (unsigned short)(r >> 16);
}
__device__ __forceinline__ unsigned char f2fp8(float x) {
    int p = __builtin_amdgcn_cvt_pk_fp8_f32(x, x, 0, false);
    return (unsigned char)(p & 0xFF);
}
__device__ __forceinline__ float2v up8lo(unsigned int w) {
    return __builtin_amdgcn_cvt_pk_f32_fp8(w, false);
}
__device__ __forceinline__ float2v up8hi(unsigned int w) {
    return __builtin_amdgcn_cvt_pk_f32_fp8(w, true);
}

__global__ void k_prepW2(const float* __restrict__ W1, const float* __restrict__ W2,
                         unsigned short* __restrict__ Wt1, unsigned short* __restrict__ Wt2) {
    const float* W = blockIdx.x ? W2 : W1;
    unsigned short* Wt = blockIdx.x ? Wt2 : Wt1;
    for (int i = threadIdx.x; i < 64 * 64; i += 256) {
        int n = i >> 6, k = i & 63;
        Wt[i] = f2bf(W[k * 64 + n]);
    }
}

// zero cursors + the Hs sentinel row (row N; ws re-poisoned per call)
__global__ void k_zeroCur(Ctx c0, Ctx c1, int nb0, int K, int N) {
    int b = blockIdx.x; Ctx c = c0;
    if (b >= nb0) { c = c1; b -= nb0; }
    int i = b * blockDim.x + threadIdx.x;
    if (i < K) c.cursorG[i * CPAD] = 0;
    if (b == 0 && threadIdx.x < 64) c.Hs[(size_t)N * 64 + threadIdx.x] = 0;
}

// binA: LDS counting sort per block, burst segment writes. 1024 threads.
__global__ __launch_bounds__(1024) void k_binA(Ctx c0, Ctx c1, int nb0, int E, int K) {
    __shared__ int cnt[KMAX];
    __shared__ int ofs[KMAX];
    __shared__ int segBase[KMAX];
    __shared__ int wsum[16];
    __shared__ unsigned int sorted[EPB];
    __shared__ unsigned short bkt[EPB];
    int b = blockIdx.x; Ctx c = c0;
    if (b >= nb0) { c = c1; b -= nb0; }
    int tid = threadIdx.x;               // 0..1023 == KMAX
    cnt[tid] = 0;
    __syncthreads();
    int base = b * EPB;
    int tot = E - base; if (tot > EPB) tot = EPB;
#pragma unroll
    for (int k = 0; k < EPB / 1024; ++k) {
        int e = base + k * 1024 + tid;
        if (e < E) atomicAdd(&cnt[c.edst[e] >> SHIFT], 1);
    }
    __syncthreads();
    int v = cnt[tid];
    int lane = tid & 63, w = tid >> 6;
    int x = v;                            // wave-inclusive scan
#pragma unroll
    for (int off = 1; off < 64; off <<= 1) {
        int t = __shfl_up(x, off, 64);
        if (lane >= off) x += t;
    }
    if (lane == 63) wsum[w] = x;
    __syncthreads();
    if (tid < 16) {
        int y = wsum[tid];
#pragma unroll
        for (int off = 1; off < 16; off <<= 1) {
            int t = __shfl_up(y, off, 16);
            if ((tid & 15) >= off) y += t;
        }
        wsum[tid] = y;                    // inclusive wave totals
    }
    __syncthreads();
    int pre = w ? wsum[w - 1] : 0;
    ofs[tid] = x + pre - v;               // exclusive scan
    if (tid < K) {
        segBase[tid] = v ? atomicAdd(&c.cursorG[tid * CPAD], v) : 0;
    } else {
        segBase[tid] = 0;
    }
    cnt[tid] = 0;
    __syncthreads();
#pragma unroll
    for (int k = 0; k < EPB / 1024; ++k) {
        int e = base + k * 1024 + tid;
        if (e < E) {
            int d = c.edst[e];
            int bk = d >> SHIFT;
            int r = atomicAdd(&cnt[bk], 1);
            int p = ofs[bk] + r;
            sorted[p] = ((unsigned int)(d & (CHUNK - 1)) << 17) | (unsigned int)c.esrc[e];
            bkt[p] = (unsigned short)bk;
        }
    }
    __syncthreads();
    for (int p = tid; p < tot; p += 1024) {
        unsigned int vv = sorted[p];
        int bk = bkt[p];
        int pos = segBase[bk] + (p - ofs[bk]);
        if (pos < CAP) c.temp[(size_t)bk * CAP + pos] = vv;
    }
}

// Per-bucket LDS counting sort -> bucket-major csr slice (stride CAP) +
// row_ptr (beg) + deg + dinv. csr stores src<<6 (pre-shifted byte offset).
__global__ __launch_bounds__(256) void k_csrb(Ctx c0, Ctx c1, int nb0, int N) {
    __shared__ int deg[CHUNK];
    __shared__ int lofs[CHUNK];
    __shared__ int cur[CHUNK];
    __shared__ int wsum2[2];
    int b = blockIdx.x; Ctx c = c0;
    if (b >= nb0) { c = c1; b -= nb0; }
    int tid = threadIdx.x;
    if (tid < CHUNK) deg[tid] = 0;
    __syncthreads();
    int cnt = c.cursorG[b * CPAD]; if (cnt > CAP) cnt = CAP;
    const size_t tb = (size_t)b * CAP;
    for (int i = tid; i < cnt; i += 256) atomicAdd(&deg[c.temp[tb + i] >> 17], 1);
    __syncthreads();
    int vdeg = 0, x = 0;
    if (tid < CHUNK) { vdeg = deg[tid]; x = vdeg; }
#pragma unroll
    for (int off = 1; off < 64; off <<= 1) {
        int t = __shfl_up(x, off, 64);
        if ((tid & 63) >= off) x += t;
    }
    if (tid < CHUNK && (tid & 63) == 63) wsum2[tid >> 6] = x;
    __syncthreads();
    int base = b * CAP;                  // bucket-major: no global scan needed
    if (tid < CHUNK) {
        int pre = (tid >> 6) ? wsum2[0] : 0;
        int excl = x + pre - vdeg;
        lofs[tid] = excl;
        cur[tid] = 0;
        int node = b * CHUNK + tid;
        if (node < N) {
            c.row_ptr[node] = base + excl;
            c.degA[node] = vdeg;
            c.dinv[node] = rsqrtf((float)vdeg + 1.0f);
        }
    }
    __syncthreads();
    for (int i = tid; i < cnt; i += 256) {
        unsigned int p = c.temp[tb + i];
        int dl = p >> 17;
        int rank = atomicAdd(&cur[dl], 1);
        c.csr[base + lofs[dl] + rank] = (p & 0x1FFFFu) << 6;   // src byte offset
    }
}

// Shared MFMA body: A-fragments provided; B from Wt; store fp8 Hs.
__device__ __forceinline__ void mfma_tail(short8 a0, short8 a1,
                                          const unsigned short* __restrict__ Wt,
                                          unsigned char* __restrict__ Hs,
                                          int row0, int r, int q, int N) {
    short8 bfrag[4][2];
#pragma unroll
    for (int ct = 0; ct < 4; ++ct)
#pragma unroll
        for (int kb = 0; kb < 2; ++kb)
            bfrag[ct][kb] = *(const short8*)(Wt + (ct * 16 + r) * 64 + q * 8 + 32 * kb);
    f32x4 acc[4];
#pragma unroll
    for (int ct = 0; ct < 4; ++ct) {
        acc[ct] = (f32x4){0.0f, 0.0f, 0.0f, 0.0f};
        acc[ct] = __builtin_amdgcn_mfma_f32_16x16x32_bf16(a0, bfrag[ct][0], acc[ct], 0, 0, 0);
        acc[ct] = __builtin_amdgcn_mfma_f32_16x16x32_bf16(a1, bfrag[ct][1], acc[ct], 0, 0, 0);
    }
#pragma unroll
    for (int reg = 0; reg < 4; ++reg) {
        int row = row0 + q * 4 + reg;
        if (row < N) {
            size_t base = (size_t)row * 64 + r;
#pragma unroll
            for (int ct = 0; ct < 4; ++ct)
                Hs[base + ct * 16] = f2fp8(acc[ct][reg]);
        }
    }
}

// GEMM1: fp32 X in, dinv folded into A-fragment conversion.
__global__ __launch_bounds__(256) void k_gemm1(Ctx c0, Ctx c1, int nb0,
                                               const unsigned short* __restrict__ Wt,
                                               int nTiles, int N) {
    int b = blockIdx.x; Ctx c = c0;
    if (b >= nb0) { c = c1; b -= nb0; }
    int wave = threadIdx.x >> 6, lane = threadIdx.x & 63;
    int tile = b * 4 + wave;
    if (tile >= nTiles) return;
    int r = lane & 15, q = lane >> 4;
    int row0 = tile * 16;
    int row = row0 + r;
    int rr = row < N ? row : N - 1;
    float d = c.dinv[rr];
    const float* xrow = c.X + (size_t)rr * 64 + q * 8;
    short8 a0, a1;
#pragma unroll
    for (int j = 0; j < 8; ++j) a0[j] = (short)f2bf(xrow[j] * d);
#pragma unroll
    for (int j = 0; j < 8; ++j) a1[j] = (short)f2bf(xrow[32 + j] * d);
    mfma_tail(a0, a1, Wt, c.Hs, row0, r, q, N);
}

// agg block mapping: XCD-partition swizzle (graph = (blockIdx>>2)&1) when
// swz, else linear split.
__device__ __forceinline__ void agg_map(int bi, int nb0, int swz,
                                        const Ctx& c0, const Ctx& c1,
                                        Ctx& c, int& b) {
    if (swz) {
        int graph = (bi >> 2) & 1;
        b = ((bi >> 3) << 2) | (bi & 3);
        c = graph ? c1 : c0;
    } else {
        b = bi; c = c0;
        if (b >= nb0) { c = c1; b -= nb0; }
    }
}

// Block-local degree-balanced slot assignment (16 nodes, LDS):
// rank by comparison count (desc); pair rank-adjacent (2q,2q+1); snake
// pairs onto waves (wave w: q=w and q=7-w). snode[slot] = local node id.
__device__ __forceinline__ void balance16(const int* __restrict__ degA,
                                          int b, int n, int tid,
                                          int* sdeg, int* snode) {
    if (tid < 16) {
        int node = b * 16 + tid;
        sdeg[tid] = (node < n) ? degA[node] : -1;
    }
    __syncthreads();
    if (tid < 16) {
        int d = sdeg[tid];
        int rank = 0;
#pragma unroll
        for (int k = 0; k < 16; ++k) {
            int dk = sdeg[k];
            rank += (dk > d) || (dk == d && k < tid);
        }
        int q = rank >> 1;
        int wv = q < 4 ? q : 7 - q;
        int pr = q < 4 ? 0 : 1;
        snode[wv * 4 + pr * 2 + (rank & 1)] = tid;
    }
    __syncthreads();
}

// 8-deep dwordx2 issue/consume windows; one window = 32 slots (4 edges
// per wave-instruction: 8 subgroups x 8 lanes x 8B). slotbase
// compile-time, lim scalar (SGPR).
__device__ __forceinline__ void agg_issue8w(const unsigned char* __restrict__ Hs,
                                            unsigned int idx, int lim,
                                            int hbase, int j, unsigned int s8,
                                            uint2v* h) {
#pragma unroll
    for (int u = 0; u < 8; ++u) {
        if (4 * u >= lim) break;              // SGPR cmp -> s_cbranch
        unsigned int su = (unsigned int)__shfl((int)idx, hbase + 4 * u + j, 64);
        h[u] = *(const uint2v*)(Hs + (su | s8));
    }
}
__device__ __forceinline__ void agg_cons8w(const uint2v* h, int lim, float2v* acc) {
#pragma unroll
    for (int u = 0; u < 8; ++u) {
        if (4 * u >= lim) break;
        acc[0] += up8lo(h[u][0]); acc[1] += up8hi(h[u][0]);   // sentinel adds 0
        acc[2] += up8lo(h[u][1]); acc[3] += up8hi(h[u][1]);
    }
}

// Two node-pairs per wave, pipelined: both cold idx loads overlap; both
// pairs' first windows are in flight before the first wait. Per half: 4
// subgroups x 8 lanes; lane s covers fp8 channels 8s..8s+7. csr holds
// src<<6; gather offset = su | (s*8). Invalid slots -> sentinel N<<6.
__device__ __forceinline__ void agg_pair2(const unsigned char* __restrict__ Hs,
                                          const unsigned int* __restrict__ csr,
                                          int beg0, int deg0, int maxs0,
                                          int beg1, int deg1, int maxs1,
                                          int lane, unsigned int sent,
                                          float2v* acc0, float2v* acc1) {
    int hbase = lane & 32;
    int hl = lane & 31;
    int j = (hl >> 3) & 3;
    unsigned int s8 = (unsigned int)((lane & 7) * 8);
    unsigned int idx0 = (hl < deg0) ? csr[beg0 + hl] : sent;
    unsigned int idx1 = (hl < deg1) ? csr[beg1 + hl] : sent;
    int lim0 = maxs0 > 32 ? 32 : maxs0;   // scalar
    int lim1 = maxs1 > 32 ? 32 : maxs1;   // scalar
    uint2v h0[8], h1[8];
    agg_issue8w(Hs, idx0, lim0, hbase, j, s8, h0);
    agg_issue8w(Hs, idx1, lim1, hbase, j, s8, h1);
    agg_cons8w(h0, lim0, acc0);
    agg_cons8w(h1, lim1, acc1);
    // rare deep tails (deg > 32)
    for (int base = 32; base < maxs0; base += 32) {
        unsigned int idx = (base + hl < deg0) ? csr[beg0 + base + hl] : sent;
        int lim = maxs0 - base; if (lim > 32) lim = 32;
        uint2v hh[8];
        agg_issue8w(Hs, idx, lim, hbase, j, s8, hh);
        agg_cons8w(hh, lim, acc0);
    }
    for (int base = 32; base < maxs1; base += 32) {
        unsigned int idx = (base + hl < deg1) ? csr[beg1 + base + hl] : sent;
        int lim = maxs1 - base; if (lim > 32) lim = 32;
        uint2v hh[8];
        agg_issue8w(Hs, idx, lim, hbase, j, s8, hh);
        agg_cons8w(hh, lim, acc1);
    }
    // merge the half's 4 subgroups (bits 3,4); does not cross halves
#pragma unroll
    for (int k = 0; k < 4; ++k) {
        float2v o;
        o.x = __shfl_xor(acc0[k].x, 8, 64);  o.y = __shfl_xor(acc0[k].y, 8, 64);
        acc0[k] += o;
        o.x = __shfl_xor(acc0[k].x, 16, 64); o.y = __shfl_xor(acc0[k].y, 16, 64);
        acc0[k] += o;
        o.x = __shfl_xor(acc1[k].x, 8, 64);  o.y = __shfl_xor(acc1[k].y, 8, 64);
        acc1[k] += o;
        o.x = __shfl_xor(acc1[k].x, 16, 64); o.y = __shfl_xor(acc1[k].y, 16, 64);
        acc1[k] += o;
    }
}

// layer-1 + fused GEMM2: block = 16 contiguous nodes, degree-balanced
// wave assignment. v = dinv * relu(b + dinv * agg); rows staged in LDS
// bf16 (XOR-swizzled at 8-element granularity), one barrier, each wave
// MFMAs one 16-col tile of W2, stores fp8 Hs2 (slot->node via snode).
__global__ __launch_bounds__(256, 8) void k_agg1(Ctx c0, Ctx c1, int nb0, int swz,
                                                 const float* __restrict__ bias,
                                                 const unsigned short* __restrict__ Wt2,
                                                 int n) {
    __shared__ unsigned short As[16][64];
    __shared__ int sdeg[16];
    __shared__ int snode[16];
    Ctx c; int b;
    agg_map(blockIdx.x, nb0, swz, c0, c1, c, b);
    int wave = threadIdx.x >> 6, lane = threadIdx.x & 63;
    int h = lane >> 5;
    int tid = threadIdx.x;
    balance16(c.degA, b, n, tid, sdeg, snode);
    int l0 = snode[wave * 4 + h];
    int l1 = snode[wave * 4 + 2 + h];
    int node0 = b * 16 + l0;
    int node1 = b * 16 + l1;
    int deg0 = sdeg[l0] < 0 ? 0 : sdeg[l0];
    int deg1 = sdeg[l1] < 0 ? 0 : sdeg[l1];
    int nd0 = node0 < n ? node0 : 0;
    int nd1 = node1 < n ? node1 : 0;
    int beg0 = c.row_ptr[nd0];
    int beg1 = c.row_ptr[nd1];
    int od0 = __shfl_xor(deg0, 32, 64); int m0 = deg0 > od0 ? deg0 : od0;
    int od1 = __shfl_xor(deg1, 32, 64); int m1 = deg1 > od1 ? deg1 : od1;
    int maxs0 = __builtin_amdgcn_readfirstlane(m0);
    int maxs1 = __builtin_amdgcn_readfirstlane(m1);
    if (b == 0 && tid < 64) c.Hs2[(size_t)n * 64 + tid] = 0;
    float2v acc0[4] = {{0.f,0.f},{0.f,0.f},{0.f,0.f},{0.f,0.f}};
    float2v acc1[4] = {{0.f,0.f},{0.f,0.f},{0.f,0.f},{0.f,0.f}};
    agg_pair2(c.Hs, c.csr, beg0, deg0, maxs0, beg1, deg1, maxs1,
              lane, (unsigned int)n << 6, acc0, acc1);
    if (((lane >> 3) & 3) == 0) {          // first subgroup of each half
        int s = lane & 7;
#pragma unroll
        for (int pr = 0; pr < 2; ++pr) {
            const float2v* ac = pr ? acc1 : acc0;
            int node = pr ? node1 : node0;
            ushort4 oA = {0, 0, 0, 0}, oB = {0, 0, 0, 0};
            if (node < n) {
                uint2v hv = *(const uint2v*)(c.Hs + (size_t)node * 64 + s * 8);
                float2v h0 = up8lo(hv[0]), h1 = up8hi(hv[0]);
                float2v h2 = up8lo(hv[1]), h3 = up8hi(hv[1]);
                float4 ba = *(const float4*)(bias + s * 8);
                float4 bb = *(const float4*)(bias + s * 8 + 4);
                float d = c.dinv[node];
                oA.x = f2bf(fmaxf(ba.x + d * (ac[0].x + h0.x), 0.0f) * d);
                oA.y = f2bf(fmaxf(ba.y + d * (ac[0].y + h0.y), 0.0f) * d);
                oA.z = f2bf(fmaxf(ba.z + d * (ac[1].x + h1.x), 0.0f) * d);
                oA.w = f2bf(fmaxf(ba.w + d * (ac[1].y + h1.y), 0.0f) * d);
                oB.x = f2bf(fmaxf(bb.x + d * (ac[2].x + h2.x), 0.0f) * d);
                oB.y = f2bf(fmaxf(bb.y + d * (ac[2].y + h2.y), 0.0f) * d);
                oB.z = f2bf(fmaxf(bb.z + d * (ac[3].x + h3.x), 0.0f) * d);
                oB.w = f2bf(fmaxf(bb.w + d * (ac[3].y + h3.y), 0.0f) * d);
            }
            int row = wave * 4 + pr * 2 + h;               // slot
            int col = (s * 8) ^ ((row & 7) << 3);
            *(ushort4*)(&As[row][col]) = oA;       // swizzled (8-elem blocks)
            *(ushort4*)(&As[row][col + 4]) = oB;
        }
    }
    __syncthreads();
    // fused GEMM2: wave handles col-tile ct = wave; slot l -> node snode[l].
    {
        int r = lane & 15, q = lane >> 4;
        int sw = (r & 7) << 3;
        short8 a0 = *(const short8*)(&As[r][(q * 8) ^ sw]);
        short8 a1 = *(const short8*)(&As[r][(q * 8 + 32) ^ sw]);
        const unsigned short* wp = Wt2 + (wave * 16 + r) * 64 + q * 8;
        short8 b0 = *(const short8*)(wp);
        short8 b1 = *(const short8*)(wp + 32);
        f32x4 acc2 = {0.0f, 0.0f, 0.0f, 0.0f};
        acc2 = __builtin_amdgcn_mfma_f32_16x16x32_bf16(a0, b0, acc2, 0, 0, 0);
        acc2 = __builtin_amdgcn_mfma_f32_16x16x32_bf16(a1, b1, acc2, 0, 0, 0);
#pragma unroll
        for (int reg = 0; reg < 4; ++reg) {
            int l = q * 4 + reg;                     // slot 0..15
            int row = b * 16 + snode[l];
            if (row < n)
                c.Hs2[(size_t)row * 64 + wave * 16 + r] = f2fp8(acc2[reg]);
        }
    }
}

// layer-2: block = 16 contiguous nodes, degree-balanced assignment;
// block-reduce 16 relu'd rows -> P[block, f] (gathers from Hs2;
// mean-pool is permutation-invariant)
__global__ __launch_bounds__(256, 8) void k_agg2(Ctx c0, Ctx c1, int nb0, int swz,
                                                 const float* __restrict__ bias, int n) {
    __shared__ float red[16 * 64];
    __shared__ int sdeg[16];
    __shared__ int snode[16];
    Ctx c; int b;
    agg_map(blockIdx.x, nb0, swz, c0, c1, c, b);
    int wave = threadIdx.x >> 6, lane = threadIdx.x & 63;
    int h = lane >> 5;
    int tid = threadIdx.x;
    balance16(c.degA, b, n, tid, sdeg, snode);
    int l0 = snode[wave * 4 + h];
    int l1 = snode[wave * 4 + 2 + h];
    int node0 = b * 16 + l0;
    int node1 = b * 16 + l1;
    int deg0 = sdeg[l0] < 0 ? 0 : sdeg[l0];
    int deg1 = sdeg[l1] < 0 ? 0 : sdeg[l1];
    int nd0 = node0 < n ? node0 : 0;
    int nd1 = node1 < n ? node1 : 0;
    int beg0 = c.row_ptr[nd0];
    int beg1 = c.row_ptr[nd1];
    int od0 = __shfl_xor(deg0, 32, 64); int m0 = deg0 > od0 ? deg0 : od0;
    int od1 = __shfl_xor(deg1, 32, 64); int m1 = deg1 > od1 ? deg1 : od1;
    int maxs0 = __builtin_amdgcn_readfirstlane(m0);
    int maxs1 = __builtin_amdgcn_readfirstlane(m1);
    float2v acc0[4] = {{0.f,0.f},{0.f,0.f},{0.f,0.f},{0.f,0.f}};
    float2v acc1[4] = {{0.f,0.f},{0.f,0.f},{0.f,0.f},{0.f,0.f}};
    agg_pair2(c.Hs2, c.csr, beg0, deg0, maxs0, beg1, deg1, maxs1,
              lane, (unsigned int)n << 6, acc0, acc1);
    if (((lane >> 3) & 3) == 0) {
        int s = lane & 7;
#pragma unroll
        for (int pr = 0; pr < 2; ++pr) {
            const float2v* ac = pr ? acc1 : acc0;
            int node = pr ? node1 : node0;
            float4 vA = {0.f, 0.f, 0.f, 0.f}, vB = {0.f, 0.f, 0.f, 0.f};
            if (node < n) {
                uint2v hv = *(const uint2v*)(c.Hs2 + (size_t)node * 64 + s * 8);
                float2v h0 = up8lo(hv[0]), h1 = up8hi(hv[0]);
                float2v h2 = up8lo(hv[1]), h3 = up8hi(hv[1]);
                float4 ba = *(const float4*)(bias + s * 8);
                float4 bb = *(const float4*)(bias + s * 8 + 4);
                float d = c.dinv[node];
                vA.x = fmaxf(ba.x + d * (ac[0].x + h0.x), 0.0f);
                vA.y = fmaxf(ba.y + d * (ac[0].y + h0.y), 0.0f);
                vA.z = fmaxf(ba.z + d * (ac[1].x + h1.x), 0.0f);
                vA.w = fmaxf(ba.w + d * (ac[1].y + h1.y), 0.0f);
                vB.x = fmaxf(bb.x + d * (ac[2].x + h2.x), 0.0f);
                vB.y = fmaxf(bb.y + d * (ac[2].y + h2.y), 0.0f);
                vB.z = fmaxf(bb.z + d * (ac[3].x + h3.x), 0.0f);
                vB.w = fmaxf(bb.w + d * (ac[3].y + h3.y), 0.0f);
            }
            int row = wave * 4 + pr * 2 + h;               // slot
            *(float4*)(&red[row * 64 + s * 8]) = vA;
            *(float4*)(&red[row * 64 + s * 8 + 4]) = vB;
        }
    }
    __syncthreads();
    if (threadIdx.x < 64) {
        float acc16 = 0.0f;
#pragma unroll
        for (int r = 0; r < 16; ++r) acc16 += red[r * 64 + threadIdx.x];
        c.P[(size_t)b * 64 + threadIdx.x] = acc16;
    }
}

// colsum -> per-block partials in P2 (no atomics, no zero pass)
__global__ void k_colsum(Ctx c0, Ctx c1, int nb0, int rows) {
    int b = blockIdx.x; Ctx c = c0;
    if (b >= nb0) { c = c1; b -= nb0; }
    int f = threadIdx.x;  // 64
    float acc = 0.0f;
    for (int r = b; r < rows; r += nb0) acc += c.P[(size_t)r * 64 + f];
    c.P2[b * 64 + f] = acc;
}

// single-wave FC: reduce 256 partial rows, then out = fcb + (S/n) @ fcw^T
__global__ void k_fc(Ctx c0, Ctx c1, const float* __restrict__ fcw,
                     const float* __restrict__ fcb, int n) {
    Ctx c = blockIdx.x ? c1 : c0;
    __shared__ float S[64];
    int j = threadIdx.x;  // 64
    float s = 0.0f;
    for (int r = 0; r < 256; ++r) s += c.P2[r * 64 + j];
    S[j] = s;
    __syncthreads();
    float inv = 1.0f / (float)n;
    float acc = fcb[j];
#pragma unroll
    for (int k = 0; k < 64; ++k) acc += (S[k] * inv) * fcw[j * 64 + k];
    c.outp[j] = acc;
}

extern "C" void kernel_launch(void* const* d_in, const int* in_sizes, int n_in,
                              void* d_out, int out_size, void* d_ws, size_t ws_size,
                              hipStream_t stream) {
    const float* x[2]  = {(const float*)d_in[0], (const float*)d_in[1]};
    const int*   ei[2] = {(const int*)d_in[2], (const int*)d_in[3]};
    const float* W1  = (const float*)d_in[4];
    const float* b1  = (const float*)d_in[5];
    const float* W2  = (const float*)d_in[6];
    const float* b2  = (const float*)d_in[7];
    const float* fcw = (const float*)d_in[8];
    const float* fcb = (const float*)d_in[9];
    float* out = (float*)d_out;

    const int N  = in_sizes[0] / 64;
    const int E  = in_sizes[2] / 2;
    const int NF = N * 64;
    const int K  = (N + CHUNK - 1) / CHUNK;     // 782 buckets
    const int gGm  = (N + 15) / 16;             // aggregate blocks (16 nodes each)
    const int gGmP = (gGm + 3) & ~3;            // padded so swizzle stays legal
    const int nTiles = (N + 15) / 16;
    const int gMf = (nTiles + 3) / 4;
    const int gBin = (E + EPB - 1) / EPB;
    const int gK  = (K + TPB - 1) / TPB;

    auto al = [](size_t x) { return (x + 127) & ~(size_t)127; };
    size_t tempB = (size_t)K * CAP * 4;
    size_t hs2B  = (size_t)NF + 64;                    // fp8 + sentinel row N
    size_t szRegion = al(tempB > hs2B ? tempB : hs2B); // Hs2 aliases temp
    size_t szHs  = al((size_t)NF + 64);                // fp8 + sentinel row N
    size_t szCsr = al((size_t)K * CAP * 4);            // bucket-major, stride CAP
    size_t szRp  = al((size_t)N * 4);                  // beg only
    size_t szDeg = al((size_t)N * 4);
    size_t szDi  = al((size_t)N * 4);
    size_t szCu  = al((size_t)K * CPAD * 4);           // padded cursors
    size_t szP   = al((size_t)gGmP * 64 * 4);
    size_t szP2  = al((size_t)256 * 64 * 4);
    size_t setB  = szRegion + szHs + szCsr + szRp + szDeg + szDi + szCu + szP + szP2;
    size_t wtB   = 2 * al(64 * 64 * 2);
    bool batched = ws_size >= wtB + 2 * setB;

    char* base = (char*)d_ws;
    unsigned short* Wt1 = (unsigned short*)base;
    unsigned short* Wt2 = (unsigned short*)(base + al(64 * 64 * 2));

    auto mkctx = [&](int g, char* p) {
        Ctx c;
        c.X = x[g]; c.esrc = ei[g]; c.edst = ei[g] + E;
        c.temp = (unsigned int*)p; c.Hs2 = (unsigned char*)p; p += szRegion;
        c.Hs = (unsigned char*)p; p += szHs;
        c.csr = (unsigned int*)p; p += szCsr;
        c.row_ptr = (int*)p; p += szRp;
        c.degA = (int*)p; p += szDeg;
        c.dinv = (float*)p; p += szDi;
        c.cursorG = (int*)p; p += szCu;
        c.P = (float*)p; p += szP;
        c.P2 = (float*)p;
        c.outp = out + g * 64;
        return c;
    };
    char* set0 = base + wtB;
    Ctx c0 = mkctx(0, set0);
    Ctx c1 = mkctx(1, batched ? set0 + setB : set0);   // fallback: shares set0

    k_prepW2<<<2, 256, 0, stream>>>(W1, W2, Wt1, Wt2);

    auto pipe = [&](Ctx A, Ctx B, int mult) {
        int swz = (mult == 2) ? 1 : 0;   // gGmP is always %4 == 0
        k_zeroCur<<<mult * gK, TPB, 0, stream>>>(A, B, gK, K, N);
        k_binA<<<mult * gBin, 1024, 0, stream>>>(A, B, gBin, E, K);
        k_csrb<<<mult * K, 256, 0, stream>>>(A, B, K, N);
        k_gemm1<<<mult * gMf, 256, 0, stream>>>(A, B, gMf, Wt1, nTiles, N);
        k_agg1<<<mult * gGmP, 256, 0, stream>>>(A, B, gGmP, swz, b1, Wt2, N);
        k_agg2<<<mult * gGmP, 256, 0, stream>>>(A, B, gGmP, swz, b2, N);
        k_colsum<<<mult * 256, 64, 0, stream>>>(A, B, 256, gGmP);
        k_fc<<<mult, 64, 0, stream>>>(A, B, fcw, fcb, N);
    };

    if (batched) {
        pipe(c0, c1, 2);
    } else {
        pipe(c0, c0, 1);   // sequential, shared buffer set
        pipe(c1, c1, 1);
    }
}

// Round 8
// 278.738 us; speedup vs baseline: 2.3939x; 1.0329x over previous
//
#include <hip/hip_runtime.h>

// SiameseGNN round 27: agg reverted to R23 (balance16 null) + single-read
// binA (register-carried edges) + single-read csrb (LDS-staged temp).
//
// Cross-round evidence: agg1 effective L2-miss-path BW is CONSTANT at
// 2.1-2.3 TB/s across R22/R23/R25/R26 (fetch/dur: 115/50.6, 115/53.0,
// 138/64.4, 115/54.9) -- the gather is at the random-64B fabric/HBM
// ceiling. MLP doubling (R23), load balance (R26) null; extra fetch
// (R25) scaled dur linearly. agg demand (205MB fp8 rows) and L2 hit
// (~58% vs ~62% capacity bound) are both ~fixed => agg at structural
// floor. Reverted to R23 exact shape.
//   fix 1 (binA): carry the 8 edges/thread in REGISTERS between the
//          histogram and placement passes -- deletes the second edst
//          read (6.4MB/graph cold) and its latency chain.
//   fix 2 (csrb): stage the <=2560-entry temp slice in LDS (10KB)
//          during the histogram pass; scatter from LDS -- deletes the
//          second temp read (6.4MB/graph).
// Everything else = R23 (dwordx2 gathers, 2 pairs/wave, scalar guards,
// fused GEMM2, pre-shifted CSR, sentinel row, fp8, wave-scan binA/csrb,
// bucket-major csr, batching, XCD swizzle).

#define TPB    256
#define CHUNK  128
#define SHIFT  7
#define KMAX   1024
#define CAP    2560
#define EPB    8192
#define CPAD   16      // cursorG stride (ints)

typedef __attribute__((ext_vector_type(8))) short short8;
typedef __attribute__((ext_vector_type(4))) float f32x4;
typedef __attribute__((ext_vector_type(2))) float float2v;
typedef __attribute__((ext_vector_type(2))) unsigned int uint2v;

struct Ctx {
    const float* X; const int* esrc; const int* edst;
    unsigned int* temp; unsigned char* Hs2; unsigned char* Hs;
    unsigned int* csr; int* row_ptr; int* degA; float* dinv; int* cursorG;
    float* P; float* P2; float* outp;
};

__device__ __forceinline__ unsigned short f2bf(float x) {
    union { float f; unsigned int i; } c; c.f = x;
    unsigned int r = c.i + 0x7FFFu + ((c.i >> 16) & 1u);   // RNE
    return (unsigned short)(r >> 16);
}
__device__ __forceinline__ unsigned char f2fp8(float x) {
    int p = __builtin_amdgcn_cvt_pk_fp8_f32(x, x, 0, false);
    return (unsigned char)(p & 0xFF);
}
__device__ __forceinline__ float2v up8lo(unsigned int w) {
    return __builtin_amdgcn_cvt_pk_f32_fp8(w, false);
}
__device__ __forceinline__ float2v up8hi(unsigned int w) {
    return __builtin_amdgcn_cvt_pk_f32_fp8(w, true);
}

__global__ void k_prepW2(const float* __restrict__ W1, const float* __restrict__ W2,
                         unsigned short* __restrict__ Wt1, unsigned short* __restrict__ Wt2) {
    const float* W = blockIdx.x ? W2 : W1;
    unsigned short* Wt = blockIdx.x ? Wt2 : Wt1;
    for (int i = threadIdx.x; i < 64 * 64; i += 256) {
        int n = i >> 6, k = i & 63;
        Wt[i] = f2bf(W[k * 64 + n]);
    }
}

// zero cursors + the Hs sentinel row (row N; ws re-poisoned per call)
__global__ void k_zeroCur(Ctx c0, Ctx c1, int nb0, int K, int N) {
    int b = blockIdx.x; Ctx c = c0;
    if (b >= nb0) { c = c1; b -= nb0; }
    int i = b * blockDim.x + threadIdx.x;
    if (i < K) c.cursorG[i * CPAD] = 0;
    if (b == 0 && threadIdx.x < 64) c.Hs[(size_t)N * 64 + threadIdx.x] = 0;
}

// binA: LDS counting sort per block, burst segment writes. 1024 threads.
// R27: edges carried in registers between passes (edst/esrc read ONCE).
__global__ __launch_bounds__(1024) void k_binA(Ctx c0, Ctx c1, int nb0, int E, int K) {
    __shared__ int cnt[KMAX];
    __shared__ int ofs[KMAX];
    __shared__ int segBase[KMAX];
    __shared__ int wsum[16];
    __shared__ unsigned int sorted[EPB];
    __shared__ unsigned short bkt[EPB];
    int b = blockIdx.x; Ctx c = c0;
    if (b >= nb0) { c = c1; b -= nb0; }
    int tid = threadIdx.x;               // 0..1023 == KMAX
    cnt[tid] = 0;
    __syncthreads();
    int base = b * EPB;
    int tot = E - base; if (tot > EPB) tot = EPB;
    int rd[EPB / 1024];
    unsigned int rs[EPB / 1024];
#pragma unroll
    for (int k = 0; k < EPB / 1024; ++k) {
        int e = base + k * 1024 + tid;
        rd[k] = -1; rs[k] = 0;
        if (e < E) {
            rd[k] = c.edst[e];
            rs[k] = (unsigned int)c.esrc[e];
            atomicAdd(&cnt[rd[k] >> SHIFT], 1);
        }
    }
    __syncthreads();
    int v = cnt[tid];
    int lane = tid & 63, w = tid >> 6;
    int x = v;                            // wave-inclusive scan
#pragma unroll
    for (int off = 1; off < 64; off <<= 1) {
        int t = __shfl_up(x, off, 64);
        if (lane >= off) x += t;
    }
    if (lane == 63) wsum[w] = x;
    __syncthreads();
    if (tid < 16) {
        int y = wsum[tid];
#pragma unroll
        for (int off = 1; off < 16; off <<= 1) {
            int t = __shfl_up(y, off, 16);
            if ((tid & 15) >= off) y += t;
        }
        wsum[tid] = y;                    // inclusive wave totals
    }
    __syncthreads();
    int pre = w ? wsum[w - 1] : 0;
    ofs[tid] = x + pre - v;               // exclusive scan
    if (tid < K) {
        segBase[tid] = v ? atomicAdd(&c.cursorG[tid * CPAD], v) : 0;
    } else {
        segBase[tid] = 0;
    }
    cnt[tid] = 0;
    __syncthreads();
#pragma unroll
    for (int k = 0; k < EPB / 1024; ++k) {
        if (rd[k] >= 0) {
            int bk = rd[k] >> SHIFT;
            int r = atomicAdd(&cnt[bk], 1);
            int p = ofs[bk] + r;
            sorted[p] = ((unsigned int)(rd[k] & (CHUNK - 1)) << 17) | rs[k];
            bkt[p] = (unsigned short)bk;
        }
    }
    __syncthreads();
    for (int p = tid; p < tot; p += 1024) {
        unsigned int vv = sorted[p];
        int bk = bkt[p];
        int pos = segBase[bk] + (p - ofs[bk]);
        if (pos < CAP) c.temp[(size_t)bk * CAP + pos] = vv;
    }
}

// Per-bucket LDS counting sort -> bucket-major csr slice (stride CAP) +
// row_ptr (beg) + deg + dinv. csr stores src<<6 (pre-shifted byte offset).
// R27: temp slice staged in LDS during histogram pass (temp read ONCE).
__global__ __launch_bounds__(256) void k_csrb(Ctx c0, Ctx c1, int nb0, int N) {
    __shared__ int deg[CHUNK];
    __shared__ int lofs[CHUNK];
    __shared__ int cur[CHUNK];
    __shared__ int wsum2[2];
    __shared__ unsigned int tl[CAP];
    int b = blockIdx.x; Ctx c = c0;
    if (b >= nb0) { c = c1; b -= nb0; }
    int tid = threadIdx.x;
    if (tid < CHUNK) deg[tid] = 0;
    __syncthreads();
    int cnt = c.cursorG[b * CPAD]; if (cnt > CAP) cnt = CAP;
    const size_t tb = (size_t)b * CAP;
    for (int i = tid; i < cnt; i += 256) {
        unsigned int vv = c.temp[tb + i];
        tl[i] = vv;
        atomicAdd(&deg[vv >> 17], 1);
    }
    __syncthreads();
    int vdeg = 0, x = 0;
    if (tid < CHUNK) { vdeg = deg[tid]; x = vdeg; }
#pragma unroll
    for (int off = 1; off < 64; off <<= 1) {
        int t = __shfl_up(x, off, 64);
        if ((tid & 63) >= off) x += t;
    }
    if (tid < CHUNK && (tid & 63) == 63) wsum2[tid >> 6] = x;
    __syncthreads();
    int base = b * CAP;                  // bucket-major: no global scan needed
    if (tid < CHUNK) {
        int pre = (tid >> 6) ? wsum2[0] : 0;
        int excl = x + pre - vdeg;
        lofs[tid] = excl;
        cur[tid] = 0;
        int node = b * CHUNK + tid;
        if (node < N) {
            c.row_ptr[node] = base + excl;
            c.degA[node] = vdeg;
            c.dinv[node] = rsqrtf((float)vdeg + 1.0f);
        }
    }
    __syncthreads();
    for (int i = tid; i < cnt; i += 256) {
        unsigned int p = tl[i];
        int dl = p >> 17;
        int rank = atomicAdd(&cur[dl], 1);
        c.csr[base + lofs[dl] + rank] = (p & 0x1FFFFu) << 6;   // src byte offset
    }
}

// Shared MFMA body: A-fragments provided; B from Wt; store fp8 Hs.
__device__ __forceinline__ void mfma_tail(short8 a0, short8 a1,
                                          const unsigned short* __restrict__ Wt,
                                          unsigned char* __restrict__ Hs,
                                          int row0, int r, int q, int N) {
    short8 bfrag[4][2];
#pragma unroll
    for (int ct = 0; ct < 4; ++ct)
#pragma unroll
        for (int kb = 0; kb < 2; ++kb)
            bfrag[ct][kb] = *(const short8*)(Wt + (ct * 16 + r) * 64 + q * 8 + 32 * kb);
    f32x4 acc[4];
#pragma unroll
    for (int ct = 0; ct < 4; ++ct) {
        acc[ct] = (f32x4){0.0f, 0.0f, 0.0f, 0.0f};
        acc[ct] = __builtin_amdgcn_mfma_f32_16x16x32_bf16(a0, bfrag[ct][0], acc[ct], 0, 0, 0);
        acc[ct] = __builtin_amdgcn_mfma_f32_16x16x32_bf16(a1, bfrag[ct][1], acc[ct], 0, 0, 0);
    }
#pragma unroll
    for (int reg = 0; reg < 4; ++reg) {
        int row = row0 + q * 4 + reg;
        if (row < N) {
            size_t base = (size_t)row * 64 + r;
#pragma unroll
            for (int ct = 0; ct < 4; ++ct)
                Hs[base + ct * 16] = f2fp8(acc[ct][reg]);
        }
    }
}

// GEMM1: fp32 X in, dinv folded into A-fragment conversion.
__global__ __launch_bounds__(256) void k_gemm1(Ctx c0, Ctx c1, int nb0,
                                               const unsigned short* __restrict__ Wt,
                                               int nTiles, int N) {
    int b = blockIdx.x; Ctx c = c0;
    if (b >= nb0) { c = c1; b -= nb0; }
    int wave = threadIdx.x >> 6, lane = threadIdx.x & 63;
    int tile = b * 4 + wave;
    if (tile >= nTiles) return;
    int r = lane & 15, q = lane >> 4;
    int row0 = tile * 16;
    int row = row0 + r;
    int rr = row < N ? row : N - 1;
    float d = c.dinv[rr];
    const float* xrow = c.X + (size_t)rr * 64 + q * 8;
    short8 a0, a1;
#pragma unroll
    for (int j = 0; j < 8; ++j) a0[j] = (short)f2bf(xrow[j] * d);
#pragma unroll
    for (int j = 0; j < 8; ++j) a1[j] = (short)f2bf(xrow[32 + j] * d);
    mfma_tail(a0, a1, Wt, c.Hs, row0, r, q, N);
}

// agg block mapping: XCD-partition swizzle (graph = (blockIdx>>2)&1) when
// swz, else linear split.
__device__ __forceinline__ void agg_map(int bi, int nb0, int swz,
                                        const Ctx& c0, const Ctx& c1,
                                        Ctx& c, int& b) {
    if (swz) {
        int graph = (bi >> 2) & 1;
        b = ((bi >> 3) << 2) | (bi & 3);
        c = graph ? c1 : c0;
    } else {
        b = bi; c = c0;
        if (b >= nb0) { c = c1; b -= nb0; }
    }
}

// 8-deep dwordx2 issue/consume windows; one window = 32 slots (4 edges
// per wave-instruction: 8 subgroups x 8 lanes x 8B). slotbase
// compile-time, lim scalar (SGPR).
__device__ __forceinline__ void agg_issue8w(const unsigned char* __restrict__ Hs,
                                            unsigned int idx, int lim,
                                            int hbase, int j, unsigned int s8,
                                            uint2v* h) {
#pragma unroll
    for (int u = 0; u < 8; ++u) {
        if (4 * u >= lim) break;              // SGPR cmp -> s_cbranch
        unsigned int su = (unsigned int)__shfl((int)idx, hbase + 4 * u + j, 64);
        h[u] = *(const uint2v*)(Hs + (su | s8));
    }
}
__device__ __forceinline__ void agg_cons8w(const uint2v* h, int lim, float2v* acc) {
#pragma unroll
    for (int u = 0; u < 8; ++u) {
        if (4 * u >= lim) break;
        acc[0] += up8lo(h[u][0]); acc[1] += up8hi(h[u][0]);   // sentinel adds 0
        acc[2] += up8lo(h[u][1]); acc[3] += up8hi(h[u][1]);
    }
}

// Two node-pairs per wave, pipelined: both cold idx loads overlap; both
// pairs' first windows are in flight before the first wait. Per half: 4
// subgroups x 8 lanes; lane s covers fp8 channels 8s..8s+7. csr holds
// src<<6; gather offset = su | (s*8). Invalid slots -> sentinel N<<6.
__device__ __forceinline__ void agg_pair2(const unsigned char* __restrict__ Hs,
                                          const unsigned int* __restrict__ csr,
                                          int beg0, int deg0, int maxs0,
                                          int beg1, int deg1, int maxs1,
                                          int lane, unsigned int sent,
                                          float2v* acc0, float2v* acc1) {
    int hbase = lane & 32;
    int hl = lane & 31;
    int j = (hl >> 3) & 3;
    unsigned int s8 = (unsigned int)((lane & 7) * 8);
    unsigned int idx0 = (hl < deg0) ? csr[beg0 + hl] : sent;
    unsigned int idx1 = (hl < deg1) ? csr[beg1 + hl] : sent;
    int lim0 = maxs0 > 32 ? 32 : maxs0;   // scalar
    int lim1 = maxs1 > 32 ? 32 : maxs1;   // scalar
    uint2v h0[8], h1[8];
    agg_issue8w(Hs, idx0, lim0, hbase, j, s8, h0);
    agg_issue8w(Hs, idx1, lim1, hbase, j, s8, h1);
    agg_cons8w(h0, lim0, acc0);
    agg_cons8w(h1, lim1, acc1);
    // rare deep tails (deg > 32)
    for (int base = 32; base < maxs0; base += 32) {
        unsigned int idx = (base + hl < deg0) ? csr[beg0 + base + hl] : sent;
        int lim = maxs0 - base; if (lim > 32) lim = 32;
        uint2v hh[8];
        agg_issue8w(Hs, idx, lim, hbase, j, s8, hh);
        agg_cons8w(hh, lim, acc0);
    }
    for (int base = 32; base < maxs1; base += 32) {
        unsigned int idx = (base + hl < deg1) ? csr[beg1 + base + hl] : sent;
        int lim = maxs1 - base; if (lim > 32) lim = 32;
        uint2v hh[8];
        agg_issue8w(Hs, idx, lim, hbase, j, s8, hh);
        agg_cons8w(hh, lim, acc1);
    }
    // merge the half's 4 subgroups (bits 3,4); does not cross halves
#pragma unroll
    for (int k = 0; k < 4; ++k) {
        float2v o;
        o.x = __shfl_xor(acc0[k].x, 8, 64);  o.y = __shfl_xor(acc0[k].y, 8, 64);
        acc0[k] += o;
        o.x = __shfl_xor(acc0[k].x, 16, 64); o.y = __shfl_xor(acc0[k].y, 16, 64);
        acc0[k] += o;
        o.x = __shfl_xor(acc1[k].x, 8, 64);  o.y = __shfl_xor(acc1[k].y, 8, 64);
        acc1[k] += o;
        o.x = __shfl_xor(acc1[k].x, 16, 64); o.y = __shfl_xor(acc1[k].y, 16, 64);
        acc1[k] += o;
    }
}

// layer-1 + fused GEMM2: block = 16 nodes (4 waves x 2 pairs). v = dinv *
// relu(b + dinv * agg); rows staged in LDS bf16 (XOR-swizzled at
// 8-element granularity), one barrier, each wave MFMAs one 16-col tile
// of W2, stores fp8 Hs2. Hs2 sentinel row N zeroed here (aliases temp).
__global__ __launch_bounds__(256, 8) void k_agg1(Ctx c0, Ctx c1, int nb0, int swz,
                                                 const float* __restrict__ bias,
                                                 const unsigned short* __restrict__ Wt2,
                                                 int n) {
    __shared__ unsigned short As[16][64];
    Ctx c; int b;
    agg_map(blockIdx.x, nb0, swz, c0, c1, c, b);
    int wave = threadIdx.x >> 6, lane = threadIdx.x & 63;
    int h = lane >> 5;
    int nbase = b * 16 + wave * 4;
    int node0 = nbase + h;
    int node1 = nbase + 2 + h;
    int nd0 = node0 < n ? node0 : 0;
    int nd1 = node1 < n ? node1 : 0;
    int beg0 = c.row_ptr[nd0];
    int beg1 = c.row_ptr[nd1];
    int deg0 = (node0 < n) ? c.degA[nd0] : 0;
    int deg1 = (node1 < n) ? c.degA[nd1] : 0;
    int od0 = __shfl_xor(deg0, 32, 64); int m0 = deg0 > od0 ? deg0 : od0;
    int od1 = __shfl_xor(deg1, 32, 64); int m1 = deg1 > od1 ? deg1 : od1;
    int maxs0 = __builtin_amdgcn_readfirstlane(m0);
    int maxs1 = __builtin_amdgcn_readfirstlane(m1);
    if (b == 0 && threadIdx.x < 64) c.Hs2[(size_t)n * 64 + threadIdx.x] = 0;
    float2v acc0[4] = {{0.f,0.f},{0.f,0.f},{0.f,0.f},{0.f,0.f}};
    float2v acc1[4] = {{0.f,0.f},{0.f,0.f},{0.f,0.f},{0.f,0.f}};
    agg_pair2(c.Hs, c.csr, beg0, deg0, maxs0, beg1, deg1, maxs1,
              lane, (unsigned int)n << 6, acc0, acc1);
    if (((lane >> 3) & 3) == 0) {          // first subgroup of each half
        int s = lane & 7;
#pragma unroll
        for (int pr = 0; pr < 2; ++pr) {
            const float2v* ac = pr ? acc1 : acc0;
            int node = nbase + pr * 2 + h;
            ushort4 oA = {0, 0, 0, 0}, oB = {0, 0, 0, 0};
            if (node < n) {
                uint2v hv = *(const uint2v*)(c.Hs + (size_t)node * 64 + s * 8);
                float2v h0 = up8lo(hv[0]), h1 = up8hi(hv[0]);
                float2v h2 = up8lo(hv[1]), h3 = up8hi(hv[1]);
                float4 ba = *(const float4*)(bias + s * 8);
                float4 bb = *(const float4*)(bias + s * 8 + 4);
                float d = c.dinv[node];
                oA.x = f2bf(fmaxf(ba.x + d * (ac[0].x + h0.x), 0.0f) * d);
                oA.y = f2bf(fmaxf(ba.y + d * (ac[0].y + h0.y), 0.0f) * d);
                oA.z = f2bf(fmaxf(ba.z + d * (ac[1].x + h1.x), 0.0f) * d);
                oA.w = f2bf(fmaxf(ba.w + d * (ac[1].y + h1.y), 0.0f) * d);
                oB.x = f2bf(fmaxf(bb.x + d * (ac[2].x + h2.x), 0.0f) * d);
                oB.y = f2bf(fmaxf(bb.y + d * (ac[2].y + h2.y), 0.0f) * d);
                oB.z = f2bf(fmaxf(bb.z + d * (ac[3].x + h3.x), 0.0f) * d);
                oB.w = f2bf(fmaxf(bb.w + d * (ac[3].y + h3.y), 0.0f) * d);
            }
            int row = wave * 4 + pr * 2 + h;
            int col = (s * 8) ^ ((row & 7) << 3);
            *(ushort4*)(&As[row][col]) = oA;       // swizzled (8-elem blocks)
            *(ushort4*)(&As[row][col + 4]) = oB;
        }
    }
    __syncthreads();
    // fused GEMM2: wave handles col-tile ct = wave; all 16 A rows valid.
    {
        int r = lane & 15, q = lane >> 4;
        int sw = (r & 7) << 3;
        short8 a0 = *(const short8*)(&As[r][(q * 8) ^ sw]);
        short8 a1 = *(const short8*)(&As[r][(q * 8 + 32) ^ sw]);
        const unsigned short* wp = Wt2 + (wave * 16 + r) * 64 + q * 8;
        short8 b0 = *(const short8*)(wp);
        short8 b1 = *(const short8*)(wp + 32);
        f32x4 acc2 = {0.0f, 0.0f, 0.0f, 0.0f};
        acc2 = __builtin_amdgcn_mfma_f32_16x16x32_bf16(a0, b0, acc2, 0, 0, 0);
        acc2 = __builtin_amdgcn_mfma_f32_16x16x32_bf16(a1, b1, acc2, 0, 0, 0);
#pragma unroll
        for (int reg = 0; reg < 4; ++reg) {
            int l = q * 4 + reg;                     // local row 0..15
            int row = b * 16 + l;
            if (row < n)
                c.Hs2[(size_t)row * 64 + wave * 16 + r] = f2fp8(acc2[reg]);
        }
    }
}

// layer-2: block = 16 nodes; block-reduce 16 relu'd rows -> P[block, f]
// (gathers from Hs2)
__global__ __launch_bounds__(256, 8) void k_agg2(Ctx c0, Ctx c1, int nb0, int swz,
                                                 const float* __restrict__ bias, int n) {
    __shared__ float red[16 * 64];
    Ctx c; int b;
    agg_map(blockIdx.x, nb0, swz, c0, c1, c, b);
    int wave = threadIdx.x >> 6, lane = threadIdx.x & 63;
    int h = lane >> 5;
    int nbase = b * 16 + wave * 4;
    int node0 = nbase + h;
    int node1 = nbase + 2 + h;
    int nd0 = node0 < n ? node0 : 0;
    int nd1 = node1 < n ? node1 : 0;
    int beg0 = c.row_ptr[nd0];
    int beg1 = c.row_ptr[nd1];
    int deg0 = (node0 < n) ? c.degA[nd0] : 0;
    int deg1 = (node1 < n) ? c.degA[nd1] : 0;
    int od0 = __shfl_xor(deg0, 32, 64); int m0 = deg0 > od0 ? deg0 : od0;
    int od1 = __shfl_xor(deg1, 32, 64); int m1 = deg1 > od1 ? deg1 : od1;
    int maxs0 = __builtin_amdgcn_readfirstlane(m0);
    int maxs1 = __builtin_amdgcn_readfirstlane(m1);
    float2v acc0[4] = {{0.f,0.f},{0.f,0.f},{0.f,0.f},{0.f,0.f}};
    float2v acc1[4] = {{0.f,0.f},{0.f,0.f},{0.f,0.f},{0.f,0.f}};
    agg_pair2(c.Hs2, c.csr, beg0, deg0, maxs0, beg1, deg1, maxs1,
              lane, (unsigned int)n << 6, acc0, acc1);
    if (((lane >> 3) & 3) == 0) {
        int s = lane & 7;
#pragma unroll
        for (int pr = 0; pr < 2; ++pr) {
            const float2v* ac = pr ? acc1 : acc0;
            int node = nbase + pr * 2 + h;
            float4 vA = {0.f, 0.f, 0.f, 0.f}, vB = {0.f, 0.f, 0.f, 0.f};
            if (node < n) {
                uint2v hv = *(const uint2v*)(c.Hs2 + (size_t)node * 64 + s * 8);
                float2v h0 = up8lo(hv[0]), h1 = up8hi(hv[0]);
                float2v h2 = up8lo(hv[1]), h3 = up8hi(hv[1]);
                float4 ba = *(const float4*)(bias + s * 8);
                float4 bb = *(const float4*)(bias + s * 8 + 4);
                float d = c.dinv[node];
                vA.x = fmaxf(ba.x + d * (ac[0].x + h0.x), 0.0f);
                vA.y = fmaxf(ba.y + d * (ac[0].y + h0.y), 0.0f);
                vA.z = fmaxf(ba.z + d * (ac[1].x + h1.x), 0.0f);
                vA.w = fmaxf(ba.w + d * (ac[1].y + h1.y), 0.0f);
                vB.x = fmaxf(bb.x + d * (ac[2].x + h2.x), 0.0f);
                vB.y = fmaxf(bb.y + d * (ac[2].y + h2.y), 0.0f);
                vB.z = fmaxf(bb.z + d * (ac[3].x + h3.x), 0.0f);
                vB.w = fmaxf(bb.w + d * (ac[3].y + h3.y), 0.0f);
            }
            int row = wave * 4 + pr * 2 + h;
            *(float4*)(&red[row * 64 + s * 8]) = vA;
            *(float4*)(&red[row * 64 + s * 8 + 4]) = vB;
        }
    }
    __syncthreads();
    if (threadIdx.x < 64) {
        float acc16 = 0.0f;
#pragma unroll
        for (int r = 0; r < 16; ++r) acc16 += red[r * 64 + threadIdx.x];
        c.P[(size_t)b * 64 + threadIdx.x] = acc16;
    }
}

// colsum -> per-block partials in P2 (no atomics, no zero pass)
__global__ void k_colsum(Ctx c0, Ctx c1, int nb0, int rows) {
    int b = blockIdx.x; Ctx c = c0;
    if (b >= nb0) { c = c1; b -= nb0; }
    int f = threadIdx.x;  // 64
    float acc = 0.0f;
    for (int r = b; r < rows; r += nb0) acc += c.P[(size_t)r * 64 + f];
    c.P2[b * 64 + f] = acc;
}

// single-wave FC: reduce 256 partial rows, then out = fcb + (S/n) @ fcw^T
__global__ void k_fc(Ctx c0, Ctx c1, const float* __restrict__ fcw,
                     const float* __restrict__ fcb, int n) {
    Ctx c = blockIdx.x ? c1 : c0;
    __shared__ float S[64];
    int j = threadIdx.x;  // 64
    float s = 0.0f;
    for (int r = 0; r < 256; ++r) s += c.P2[r * 64 + j];
    S[j] = s;
    __syncthreads();
    float inv = 1.0f / (float)n;
    float acc = fcb[j];
#pragma unroll
    for (int k = 0; k < 64; ++k) acc += (S[k] * inv) * fcw[j * 64 + k];
    c.outp[j] = acc;
}

extern "C" void kernel_launch(void* const* d_in, const int* in_sizes, int n_in,
                              void* d_out, int out_size, void* d_ws, size_t ws_size,
                              hipStream_t stream) {
    const float* x[2]  = {(const float*)d_in[0], (const float*)d_in[1]};
    const int*   ei[2] = {(const int*)d_in[2], (const int*)d_in[3]};
    const float* W1  = (const float*)d_in[4];
    const float* b1  = (const float*)d_in[5];
    const float* W2  = (const float*)d_in[6];
    const float* b2  = (const float*)d_in[7];
    const float* fcw = (const float*)d_in[8];
    const float* fcb = (const float*)d_in[9];
    float* out = (float*)d_out;

    const int N  = in_sizes[0] / 64;
    const int E  = in_sizes[2] / 2;
    const int NF = N * 64;
    const int K  = (N + CHUNK - 1) / CHUNK;     // 782 buckets
    const int gGm  = (N + 15) / 16;             // aggregate blocks (16 nodes each)
    const int gGmP = (gGm + 3) & ~3;            // padded so swizzle stays legal
    const int nTiles = (N + 15) / 16;
    const int gMf = (nTiles + 3) / 4;
    const int gBin = (E + EPB - 1) / EPB;
    const int gK  = (K + TPB - 1) / TPB;

    auto al = [](size_t x) { return (x + 127) & ~(size_t)127; };
    size_t tempB = (size_t)K * CAP * 4;
    size_t hs2B  = (size_t)NF + 64;                    // fp8 + sentinel row N
    size_t szRegion = al(tempB > hs2B ? tempB : hs2B); // Hs2 aliases temp
    size_t szHs  = al((size_t)NF + 64);                // fp8 + sentinel row N
    size_t szCsr = al((size_t)K * CAP * 4);            // bucket-major, stride CAP
    size_t szRp  = al((size_t)N * 4);                  // beg only
    size_t szDeg = al((size_t)N * 4);
    size_t szDi  = al((size_t)N * 4);
    size_t szCu  = al((size_t)K * CPAD * 4);           // padded cursors
    size_t szP   = al((size_t)gGmP * 64 * 4);
    size_t szP2  = al((size_t)256 * 64 * 4);
    size_t setB  = szRegion + szHs + szCsr + szRp + szDeg + szDi + szCu + szP + szP2;
    size_t wtB   = 2 * al(64 * 64 * 2);
    bool batched = ws_size >= wtB + 2 * setB;

    char* base = (char*)d_ws;
    unsigned short* Wt1 = (unsigned short*)base;
    unsigned short* Wt2 = (unsigned short*)(base + al(64 * 64 * 2));

    auto mkctx = [&](int g, char* p) {
        Ctx c;
        c.X = x[g]; c.esrc = ei[g]; c.edst = ei[g] + E;
        c.temp = (unsigned int*)p; c.Hs2 = (unsigned char*)p; p += szRegion;
        c.Hs = (unsigned char*)p; p += szHs;
        c.csr = (unsigned int*)p; p += szCsr;
        c.row_ptr = (int*)p; p += szRp;
        c.degA = (int*)p; p += szDeg;
        c.dinv = (float*)p; p += szDi;
        c.cursorG = (int*)p; p += szCu;
        c.P = (float*)p; p += szP;
        c.P2 = (float*)p;
        c.outp = out + g * 64;
        return c;
    };
    char* set0 = base + wtB;
    Ctx c0 = mkctx(0, set0);
    Ctx c1 = mkctx(1, batched ? set0 + setB : set0);   // fallback: shares set0

    k_prepW2<<<2, 256, 0, stream>>>(W1, W2, Wt1, Wt2);

    auto pipe = [&](Ctx A, Ctx B, int mult) {
        int swz = (mult == 2) ? 1 : 0;   // gGmP is always %4 == 0
        k_zeroCur<<<mult * gK, TPB, 0, stream>>>(A, B, gK, K, N);
        k_binA<<<mult * gBin, 1024, 0, stream>>>(A, B, gBin, E, K);
        k_csrb<<<mult * K, 256, 0, stream>>>(A, B, K, N);
        k_gemm1<<<mult * gMf, 256, 0, stream>>>(A, B, gMf, Wt1, nTiles, N);
        k_agg1<<<mult * gGmP, 256, 0, stream>>>(A, B, gGmP, swz, b1, Wt2, N);
        k_agg2<<<mult * gGmP, 256, 0, stream>>>(A, B, gGmP, swz, b2, N);
        k_colsum<<<mult * 256, 64, 0, stream>>>(A, B, 256, gGmP);
        k_fc<<<mult, 64, 0, stream>>>(A, B, fcw, fcb, N);
    };

    if (batched) {
        pipe(c0, c1, 2);
    } else {
        pipe(c0, c0, 1);   // sequential, shared buffer set
        pipe(c1, c1, 1);
    }
}